// Round 7
// baseline (1270.784 us; speedup 1.0000x reference)
//
#include <hip/hip_runtime.h>

typedef unsigned short ushort_t;
typedef unsigned int uint_t;
typedef unsigned long long ull_t;
typedef __attribute__((ext_vector_type(8))) short short8;
typedef __attribute__((ext_vector_type(4))) float f32x4;

#define B_ 1024
#define N_ 64
#define H_ 128
#define NT 256

// bf16 weight-image element offsets
#define IMG_WI 0
#define IMG_WJ 16384
#define IMG_UW 32768
#define IMG_GS 49152
#define IMG_FT 65536
#define IMG_FB 81920
#define IMG_C1 98304
#define IMG_C2 163840
#define IMG_GMT 229376
#define IMG_RW 245760
#define IMG_L 249856
#define IMG_FO 999424

__device__ __forceinline__ ushort_t f2bf(float f) {
    // native RNE f32->bf16; bit-identical to the integer RNE sequence.
    return __builtin_bit_cast(ushort_t, (__bf16)f);
}
__device__ __forceinline__ float bf2f(ushort_t u) {
    union { uint_t i; float f; } v; v.i = ((uint_t)u) << 16; return v.f;
}
__device__ __forceinline__ float siluf(float x) { return x / (1.0f + __expf(-x)); }

// LDS swizzle: 16B-chunk c of row m stored at chunk c ^ (m&7)
__device__ __forceinline__ int sidx(int m, int k) {
    return m * H_ + (((k >> 3) ^ (m & 7)) << 3) + (k & 7);
}
__device__ __forceinline__ int fragoff(int m, int ch) {
    return m * H_ + ((ch ^ (m & 7)) << 3);
}

// ========== preamble: f32 weights -> transposed bf16 images ==============
// LDS 128x32 tile transpose. Reads coalesced (32x4B rows), writes
// vectorized 2x16B per thread.
extern "C" __global__ __launch_bounds__(256)
void convert_weights(const float* __restrict__ msg_W, const float* __restrict__ upd_W,
                     const float* __restrict__ gself_W, const float* __restrict__ fus_W,
                     const float* __restrict__ cb_W1, const float* __restrict__ cb_W2,
                     const float* __restrict__ gmean_W, const float* __restrict__ fo_W1,
                     ushort_t* __restrict__ wimg)
{
    __shared__ ushort_t tile[128][34];
    const int g = blockIdx.x;
    const int tid = threadIdx.x;
    const float* W; int ld = 128, k0 = 0, c0; ushort_t* dst;
    if (g >= 244) {
        int st = g - 244;
        W = fo_W1; c0 = st * 32; dst = wimg + IMG_FO + st * 4096;
    } else {
        const int l = g / 61, r = g - l * 61;
        ushort_t* base = wimg + l * IMG_L;
        if (r == 60) {                   // rW pad image: 4 sub-stages [32f][32k]
            const float* Wr = msg_W + l * 35328 + 256 * 128;
            ushort_t* drw = base + IMG_RW;
            for (int e = 0; e < 16; ++e) {
                int q = threadIdx.x * 16 + e;
                int sub = q >> 10, n = (q >> 5) & 31, k = q & 31;
                drw[q] = f2bf(k < 20 ? Wr[(size_t)k * 128 + sub * 32 + n] : 0.0f);
            }
            return;
        }
        int off, st;
        if      (r < 4)  { W = msg_W + l * 35328;            st = r;      off = IMG_WI;  c0 = st * 32; }
        else if (r < 8)  { W = msg_W + l * 35328;  k0 = 128; st = r - 4;  off = IMG_WJ;  c0 = st * 32; }
        else if (r < 12) { W = upd_W + l * 16384;            st = r - 8;  off = IMG_UW;  c0 = st * 32; }
        else if (r < 16) { W = gself_W + l * 16384;          st = r - 12; off = IMG_GS;  c0 = st * 32; }
        else if (r < 20) { W = fus_W + l * 32768;            st = r - 16; off = IMG_FT;  c0 = st * 32; }
        else if (r < 24) { W = fus_W + l * 32768;  k0 = 128; st = r - 20; off = IMG_FB;  c0 = st * 32; }
        else if (r < 40) { W = cb_W1 + l * 65536;  ld = 512; st = r - 24; off = IMG_C1;  c0 = st * 32; }
        else if (r < 56) { int j = (r - 40) >> 2; W = cb_W2 + l * 65536; k0 = j * 128;
                           st = r - 40; off = IMG_C2; c0 = ((r - 40) & 3) * 32; }
        else             { W = gmean_W + l * 16384;          st = r - 56; off = IMG_GMT; c0 = st * 32; }
        dst = base + off + st * 4096;
    }
    const int kr = tid >> 5, n = tid & 31;
    #pragma unroll
    for (int p = 0; p < 16; ++p) {
        int k = p * 8 + kr;
        tile[k][n] = f2bf(W[(size_t)(k0 + k) * ld + c0 + n]);
    }
    __syncthreads();
    {
        int n2 = tid >> 3, kk = (tid & 7) << 4;
        short8 v0, v1;
        #pragma unroll
        for (int e = 0; e < 8; ++e) v0[e] = (short)tile[kk + e][n2];
        #pragma unroll
        for (int e = 0; e < 8; ++e) v1[e] = (short)tile[kk + 8 + e][n2];
        *(short8*)(dst + n2 * 128 + kk) = v0;
        *(short8*)(dst + n2 * 128 + kk + 8) = v1;
    }
}

// ========== main fused kernel ==============================================
// R5 structure (best: 1197us) + LDS DIET: d[]/env[] deleted, idx u16->u8.
// D recomputes ddm/ev from persistent spos via the BIT-IDENTICAL op sequence
// kNN used ((a-b)^2 sign-exact; min-reduce returns element bits; same
// sqrtf/fmaxf/__cosf chain) -- numerically exact vs stored d/env.
// LDS 61440 -> 52992: 3 blocks/CU (159744 <= 160K) at the same 128-reg cap
// (512/128 = 4 waves/SIMD allowed) -> 3 waves/SIMD, +50% TLP. Occupancy was
// LDS-bound, not reg-bound: this is the first occupancy lever with no new
// spill exposure.
struct __align__(16) Smem {
    ushort_t T1[N_ * H_];   // 16384B  scratch image (Gm/msum/glob/xhat)
    ushort_t T2[N_ * H_];   // 16384B  scratch image (hj/local/C1)
    ushort_t T3[N_ * H_];   // 16384B  layer-input h image
    float spos[192];        //   768B  positions (persistent: D recompute)
    unsigned char idx[1024];//  1024B  neighbor indices (u8, <64)
    char u[2048];           // part bf16[512] | hmean f32[128]@1024 | gvec@1536
};

// one output stage s (16 cols, col = s*16+l15), K=128: 4 B-frags from global
__device__ __forceinline__ f32x4 gemm_s(const short8 a[4], const ushort_t* __restrict__ img,
                                        int s, int l15, int quad)
{
    const ushort_t* base = img + ((s >> 1) << 12) + ((((s & 1) << 4) + l15) << 7) + quad * 8;
    short8 b0 = *(const short8*)(base);
    short8 b1 = *(const short8*)(base + 32);
    short8 b2 = *(const short8*)(base + 64);
    short8 b3 = *(const short8*)(base + 96);
    f32x4 c = {0.f, 0.f, 0.f, 0.f};
    c = __builtin_amdgcn_mfma_f32_16x16x32_bf16(a[0], b0, c, 0, 0, 0);
    c = __builtin_amdgcn_mfma_f32_16x16x32_bf16(a[1], b1, c, 0, 0, 0);
    c = __builtin_amdgcn_mfma_f32_16x16x32_bf16(a[2], b2, c, 0, 0, 0);
    c = __builtin_amdgcn_mfma_f32_16x16x32_bf16(a[3], b3, c, 0, 0, 0);
    return c;
}
__device__ __forceinline__ f32x4 gemm_s_acc(const short8 a[4], const ushort_t* __restrict__ img,
                                            int s, int l15, int quad, f32x4 c)
{
    const ushort_t* base = img + ((s >> 1) << 12) + ((((s & 1) << 4) + l15) << 7) + quad * 8;
    short8 b0 = *(const short8*)(base);
    short8 b1 = *(const short8*)(base + 32);
    short8 b2 = *(const short8*)(base + 64);
    short8 b3 = *(const short8*)(base + 96);
    c = __builtin_amdgcn_mfma_f32_16x16x32_bf16(a[0], b0, c, 0, 0, 0);
    c = __builtin_amdgcn_mfma_f32_16x16x32_bf16(a[1], b1, c, 0, 0, 0);
    c = __builtin_amdgcn_mfma_f32_16x16x32_bf16(a[2], b2, c, 0, 0, 0);
    c = __builtin_amdgcn_mfma_f32_16x16x32_bf16(a[3], b3, c, 0, 0, 0);
    return c;
}
__device__ __forceinline__ void loadA(const ushort_t* __restrict__ X, int mrow, int quad, short8 a[4]) {
    #pragma unroll
    for (int kc = 0; kc < 4; ++kc) a[kc] = *(const short8*)&X[fragoff(mrow, kc * 4 + quad)];
}

extern "C" __global__ __launch_bounds__(NT, 2)
void md17_fused_kernel(
    const float* __restrict__ positions, const int* __restrict__ atomic_numbers,
    const float* __restrict__ atom_embed, const float* __restrict__ pos_W,
    const float* __restrict__ pos_b,
    const float* __restrict__ msg_b, const float* __restrict__ upd_b,
    const float* __restrict__ g_b, const float* __restrict__ fus_b,
    const float* __restrict__ ln_g, const float* __restrict__ ln_b,
    const float* __restrict__ cb_b1, const float* __restrict__ cb_b2,
    const float* __restrict__ fo_b1,
    const float* __restrict__ fo_W2, const float* __restrict__ fo_b2,
    char* __restrict__ ws, float* __restrict__ out)
{
    __shared__ Smem sm;
    const int b = blockIdx.x;
    const int tid = threadIdx.x;
    const int wave = tid >> 6, lane = tid & 63;
    const int quad = lane >> 4, l15 = lane & 15;
    const int mrow = wave * 16 + l15;       // A-frag row (wave-owned)
    const int rbase = wave * 16 + quad * 4; // C-tile row base (wave-owned)

    const ushort_t* wimg = (const ushort_t*)ws;
    float* spos = sm.spos;
    ushort_t* part = (ushort_t*)sm.u;       // [4][128] bf16 hmean partials
    float* hmean = (float*)(sm.u + 1024);
    float* gvec  = (float*)(sm.u + 1536);

    // residual stream, C-frag layout: hreg[s][r] = h[rbase+r][s*16+l15]
    float hreg[8][4];

    // ---- setup: positions -> LDS ----
    if (tid < 192) spos[tid] = positions[b * 192 + tid];
    __syncthreads();

    // ---- quad-parallel inline kNN: 16-lane group per atom; stores idx only --
    {
        // candidates: lane owns atoms l15*4 .. l15*4+3 (lane order = index order)
        float cx[4], cy[4], cz[4];
        #pragma unroll
        for (int j = 0; j < 4; ++j) {
            cx[j] = spos[(l15 * 4 + j) * 3 + 0];
            cy[j] = spos[(l15 * 4 + j) * 3 + 1];
            cz[j] = spos[(l15 * 4 + j) * 3 + 2];
        }
        #pragma unroll 1
        for (int it = 0; it < 4; ++it) {
            const int n = wave * 16 + it * 4 + quad;   // this quad-group's atom
            float nx = spos[n * 3 + 0], ny = spos[n * 3 + 1], nz = spos[n * 3 + 2];
            float d2[4];
            #pragma unroll
            for (int j = 0; j < 4; ++j) {
                float dx = __fsub_rn(nx, cx[j]);
                float dy = __fsub_rn(ny, cy[j]);
                float dz = __fsub_rn(nz, cz[j]);
                d2[j] = __fadd_rn(__fadd_rn(__fmul_rn(dx, dx), __fmul_rn(dy, dy)),
                                  __fmul_rn(dz, dz));
                if (l15 * 4 + j == n) d2[j] = 1e30f;   // exclude self
            }
            #pragma unroll 1
            for (int k = 0; k < 16; ++k) {
                // strict < keeps lowest j on intra-lane ties
                float lm = d2[0];
                if (d2[1] < lm) lm = d2[1];
                if (d2[2] < lm) lm = d2[2];
                if (d2[3] < lm) lm = d2[3];
                float gm = lm;
                #pragma unroll
                for (int o = 1; o < 16; o <<= 1) gm = fminf(gm, __shfl_xor(gm, o));
                ull_t bal = __ballot(lm == gm);
                int wl = __ffsll((bal >> (quad * 16)) & 0xFFFFull) - 1;  // lowest lane
                if (l15 == wl) {
                    int jstar = 3;                      // lowest matching slot
                    if (d2[2] == gm) jstar = 2;
                    if (d2[1] == gm) jstar = 1;
                    if (d2[0] == gm) jstar = 0;
                    #pragma unroll
                    for (int j = 0; j < 4; ++j) if (j == jstar) d2[j] = 1e30f;
                    sm.idx[n * 16 + k] = (unsigned char)(wl * 4 + jstar);
                }
            }
        }
    }

    // ---- embeddings, per-lane into hreg + T3 image ----
    {
        int an[4];
        #pragma unroll
        for (int r = 0; r < 4; ++r) an[r] = atomic_numbers[b * N_ + rbase + r];
        #pragma unroll
        for (int s = 0; s < 8; ++s) {
            int col = s * 16 + l15;
            #pragma unroll
            for (int r = 0; r < 4; ++r) {
                float v;
                if (s < 2) {                        // col < 32: atom-type embed
                    v = atom_embed[an[r] * 32 + col];
                } else {                            // col >= 32: position MLP
                    int j = col - 32;
                    v = pos_b[j];
                    #pragma unroll
                    for (int c = 0; c < 3; ++c)
                        v = fmaf(spos[(rbase + r) * 3 + c], pos_W[c * 96 + j], v);
                }
                hreg[s][r] = v;
                sm.T3[sidx(rbase + r, col)] = f2bf(v);
            }
        }
    }
    __syncthreads();
    // layer-0 hmean partials (stage A folded out of the loop)
    #pragma unroll
    for (int s = 0; s < 8; ++s) {
        int col = s * 16 + l15;
        float p = hreg[s][0] + hreg[s][1] + hreg[s][2] + hreg[s][3];
        p += __shfl_xor(p, 16);
        p += __shfl_xor(p, 32);
        if (quad == 0) part[wave * 128 + col] = f2bf(p);
    }

    #pragma unroll 1
    for (int l = 0; l < 4; ++l) {
        const ushort_t* wl = wimg + l * IMG_L;
        const float* mb  = msg_b + l * H_;
        const float* ub  = upd_b + l * H_;
        const float* gb  = g_b + l * H_;
        const float* fb  = fus_b + l * H_;
        const float* lg  = ln_g + l * H_;
        const float* lb  = ln_b + l * H_;
        const float* c1b = cb_b1 + l * 4 * H_;
        const float* c2b = cb_b2 + l * H_;

        __syncthreads();                                 // B1 (part visible)
        if (tid < H_)
            hmean[tid] = (bf2f(part[tid]) + bf2f(part[128 + tid])
                        + bf2f(part[256 + tid]) + bf2f(part[384 + tid])) * (1.0f / 64.0f);
        __syncthreads();                                 // B2

        // C: gvec GEMV (tid<128) ; a_h from T3 ; WI -> T1 (+mb) ; WJ -> T2
        if (tid < H_) {
            float s = gb[tid];
            const ushort_t* wrow = wl + IMG_GMT + tid * 128;
            for (int c = 0; c < 128; c += 8) {
                short8 w = *(const short8*)(wrow + c);
                #pragma unroll
                for (int i = 0; i < 8; ++i) s = fmaf(hmean[c + i], bf2f((ushort_t)w[i]), s);
            }
            gvec[tid] = s;
        }
        {
            short8 a_h[4]; loadA(sm.T3, mrow, quad, a_h);
            #pragma unroll 2
            for (int s = 0; s < 8; ++s) {
                f32x4 c = gemm_s(a_h, wl + IMG_WI, s, l15, quad);
                int col = s * 16 + l15; float bv = mb[col];
                #pragma unroll
                for (int r = 0; r < 4; ++r)
                    sm.T1[sidx(rbase + r, col)] = f2bf(c[r] + bv);
            }
            #pragma unroll 2
            for (int s = 0; s < 8; ++s) {
                f32x4 c = gemm_s(a_h, wl + IMG_WJ, s, l15, quad);
                int col = s * 16 + l15;
                #pragma unroll
                for (int r = 0; r < 4; ++r)
                    sm.T2[sidx(rbase + r, col)] = f2bf(c[r]);
            }
        }
        __syncthreads();                                 // B3 (Gm visible to all)

        // D: msum — whole wave per atom n = wave*16+g (own rows), in place in T1.
        // ddm/ev recomputed from spos+idx (bit-identical to the old stored d/env).
        {
            float ccv[8];
            #pragma unroll
            for (int j = 0; j < 8; ++j)
                ccv[j] = (float)((double)(quad * 8 + j) * (5.0 / 19.0));
            #pragma unroll 1
            for (int g = 0; g < 16; ++g) {
                int n = wave * 16 + g;
                float nx = spos[n * 3 + 0], ny = spos[n * 3 + 1], nz = spos[n * 3 + 2];
                int jv[4]; float ev[4];
                #pragma unroll
                for (int r = 0; r < 4; ++r) {
                    int j = sm.idx[n * 16 + quad * 4 + r];
                    jv[r] = j;
                    float dx = __fsub_rn(nx, spos[j * 3 + 0]);
                    float dy = __fsub_rn(ny, spos[j * 3 + 1]);
                    float dz = __fsub_rn(nz, spos[j * 3 + 2]);
                    float d2 = __fadd_rn(__fadd_rn(__fmul_rn(dx, dx), __fmul_rn(dy, dy)),
                                         __fmul_rn(dz, dz));
                    float dd = sqrtf(fmaxf(d2, 1e-12f));
                    ev[r] = (dd < 5.0f)
                        ? 0.5f * (__cosf(0.62831853071795864769f * dd) + 1.0f) : 0.0f;
                }
                float ddm;
                {
                    int j = sm.idx[n * 16 + l15];
                    float dx = __fsub_rn(nx, spos[j * 3 + 0]);
                    float dy = __fsub_rn(ny, spos[j * 3 + 1]);
                    float dz = __fsub_rn(nz, spos[j * 3 + 2]);
                    float d2 = __fadd_rn(__fadd_rn(__fmul_rn(dx, dx), __fmul_rn(dy, dy)),
                                         __fmul_rn(dz, dz));
                    ddm = sqrtf(fmaxf(d2, 1e-12f));
                }
                short8 arb;
                #pragma unroll
                for (int j = 0; j < 8; ++j) {
                    float t2 = ddm - ccv[j];
                    float rv = __expf(-10.0f * t2 * t2);
                    arb[j] = (short)((quad * 8 + j) < 20 ? f2bf(rv) : (ushort_t)0);
                }
                #pragma unroll
                for (int s = 0; s < 8; ++s) {
                    int col = s * 16 + l15;
                    const ushort_t* rbase_p = wl + IMG_RW + ((s >> 1) << 10)
                                            + ((((s & 1) << 4) + l15) << 5) + quad * 8;
                    short8 brw = *(const short8*)rbase_p;
                    f32x4 c = {0.f, 0.f, 0.f, 0.f};
                    c = __builtin_amdgcn_mfma_f32_16x16x32_bf16(arb, brw, c, 0, 0, 0);
                    float ai = bf2f(sm.T1[sidx(n, col)]);
                    float acc = 0.f;
                    #pragma unroll
                    for (int r = 0; r < 4; ++r) {
                        float gm = bf2f(sm.T2[sidx(jv[r], col)]);
                        acc = fmaf(siluf(ai + gm + c[r]), ev[r], acc);
                    }
                    acc += __shfl_xor(acc, 16);
                    acc += __shfl_xor(acc, 32);
                    if (quad == 0) sm.T1[sidx(n, col)] = f2bf(acc);
                }
            }
        }
        __syncthreads();                                 // B4 (Gm reads done; T2 free)

        // ---- free-run region: everything below touches only own rows ----

        // F: UW(a_m)+hreg -> T2 local ; GS(a_h reloaded from T3) + gvec -> T1 glob
        {
            short8 a_m[4]; loadA(sm.T1, mrow, quad, a_m);
            #pragma unroll
            for (int s = 0; s < 8; ++s) {
                f32x4 c = gemm_s(a_m, wl + IMG_UW, s, l15, quad);
                int col = s * 16 + l15; float bv = ub[col];
                #pragma unroll
                for (int r = 0; r < 4; ++r)
                    sm.T2[sidx(rbase + r, col)] = f2bf(hreg[s][r] + siluf(c[r] + bv));
            }
            short8 a_h[4]; loadA(sm.T3, mrow, quad, a_h);
            #pragma unroll 2
            for (int s = 0; s < 8; ++s) {
                f32x4 c = gemm_s(a_h, wl + IMG_GS, s, l15, quad);
                int col = s * 16 + l15; float gv = gvec[col];
                #pragma unroll
                for (int r = 0; r < 4; ++r)
                    sm.T1[sidx(rbase + r, col)] = f2bf(siluf(c[r] + gv));
            }
        }

        // G: fused = silu([local|glob]@[FT;FB]+fb) -> hreg ; LN sums in regs
        float sr[4] = {0.f, 0.f, 0.f, 0.f}, qr[4] = {0.f, 0.f, 0.f, 0.f};
        {
            short8 a_t[4];
            loadA(sm.T2, mrow, quad, a_t);               // local
            #pragma unroll
            for (int s = 0; s < 8; ++s) {
                f32x4 c = gemm_s(a_t, wl + IMG_FT, s, l15, quad);
                #pragma unroll
                for (int r = 0; r < 4; ++r) hreg[s][r] = c[r];  // residual h is dead here
            }
            loadA(sm.T1, mrow, quad, a_t);               // glob
            #pragma unroll
            for (int s = 0; s < 8; ++s) {
                f32x4 c = gemm_s(a_t, wl + IMG_FB, s, l15, quad);
                int col = s * 16 + l15; float bv = fb[col];
                #pragma unroll
                for (int r = 0; r < 4; ++r) {
                    float v = siluf(hreg[s][r] + c[r] + bv);
                    hreg[s][r] = v;
                    sr[r] += v; qr[r] += v * v;
                }
            }
            #pragma unroll
            for (int o = 1; o < 16; o <<= 1) {
                #pragma unroll
                for (int r = 0; r < 4; ++r) {
                    sr[r] += __shfl_xor(sr[r], o);
                    qr[r] += __shfl_xor(qr[r], o);
                }
            }
        }

        // H: LN normalize (wave-local) -> T1 (x-hat)
        #pragma unroll
        for (int r = 0; r < 4; ++r) {
            float mu = sr[r] * (1.0f / 128.0f);
            float var = qr[r] * (1.0f / 128.0f) - mu * mu;
            float rs = rsqrtf(var + 1e-5f);
            int row = rbase + r;
            #pragma unroll
            for (int s = 0; s < 8; ++s) {
                int col = s * 16 + l15;
                sm.T1[sidx(row, col)] = f2bf((hreg[s][r] - mu) * rs * lg[col] + lb[col]);
            }
        }

        // J: Clifford MLP, 4 K-chunks; C1 -> T2; C2 accumulates into acc2.
        // acc2 SEEDED with residual + c2b (hreg dead across j-loop); a_x
        // reloaded from T1 each chunk.
        {
            f32x4 acc2[8];
            #pragma unroll
            for (int s = 0; s < 8; ++s) {
                int col = s * 16 + l15; float bv = c2b[col];
                #pragma unroll
                for (int r = 0; r < 4; ++r) acc2[s][r] = hreg[s][r] + bv;
            }
            #pragma unroll 1
            for (int j = 0; j < 4; ++j) {
                short8 a_x[4]; loadA(sm.T1, mrow, quad, a_x);
                #pragma unroll 2
                for (int s = 0; s < 8; ++s) {
                    f32x4 c = gemm_s(a_x, wl + IMG_C1 + j * 16384, s, l15, quad);
                    int col = s * 16 + l15; float bv = c1b[j * H_ + col];
                    #pragma unroll
                    for (int r = 0; r < 4; ++r)
                        sm.T2[sidx(rbase + r, col)] = f2bf(siluf(c[r] + bv));
                }
                short8 a_t[4]; loadA(sm.T2, mrow, quad, a_t);
                #pragma unroll
                for (int s = 0; s < 8; ++s)
                    acc2[s] = gemm_s_acc(a_t, wl + IMG_C2 + j * 16384, s, l15, quad, acc2[s]);
            }
            // K: h_next = acc2 -> hreg + T3 image ; fold next-layer hmean partials
            #pragma unroll
            for (int s = 0; s < 8; ++s) {
                int col = s * 16 + l15;
                float p = 0.f;
                #pragma unroll
                for (int r = 0; r < 4; ++r) {
                    float v = acc2[s][r];
                    hreg[s][r] = v;
                    sm.T3[sidx(rbase + r, col)] = f2bf(v);
                    p += v;
                }
                p += __shfl_xor(p, 16);
                p += __shfl_xor(p, 32);
                if (quad == 0) part[wave * 128 + col] = f2bf(p);
            }
        }
        // no layer-end barrier: B1 at next layer top covers part/T3 visibility
    }

    // ---- head: FO -> T2 (own rows, no barrier) ; barrier ; gather -> out ----
    {
        short8 a_f[4]; loadA(sm.T3, mrow, quad, a_f);
        #pragma unroll 2
        for (int s = 0; s < 8; ++s) {
            f32x4 c = gemm_s(a_f, wimg + IMG_FO, s, l15, quad);
            int col = s * 16 + l15; float bv = fo_b1[col];
            #pragma unroll
            for (int r = 0; r < 4; ++r)
                sm.T2[sidx(rbase + r, col)] = f2bf(siluf(c[r] + bv));
        }
    }
    __syncthreads();
    if (tid < 192) {
        int n = tid / 3, j = tid - n * 3;
        float s = fo_b2[j];
        #pragma unroll 1
        for (int ch = 0; ch < 16; ++ch) {
            short8 v = *(const short8*)&sm.T2[fragoff(n, ch)];
            #pragma unroll
            for (int i = 0; i < 8; ++i)
                s = fmaf(bf2f((ushort_t)v[i]), fo_W2[(ch * 8 + i) * 3 + j], s);
        }
        out[b * 192 + tid] = s;
    }
}

extern "C" void kernel_launch(void* const* d_in, const int* in_sizes, int n_in,
                              void* d_out, int out_size, void* d_ws, size_t ws_size,
                              hipStream_t stream) {
    (void)in_sizes; (void)n_in; (void)out_size; (void)ws_size;
    convert_weights<<<248, 256, 0, stream>>>(
        (const float*)d_in[5], (const float*)d_in[7], (const float*)d_in[9],
        (const float*)d_in[12], (const float*)d_in[16], (const float*)d_in[18],
        (const float*)d_in[10], (const float*)d_in[20], (ushort_t*)d_ws);
    md17_fused_kernel<<<B_, NT, 0, stream>>>(
        (const float*)d_in[0], (const int*)d_in[1],
        (const float*)d_in[2], (const float*)d_in[3], (const float*)d_in[4],
        (const float*)d_in[6], (const float*)d_in[8],
        (const float*)d_in[11], (const float*)d_in[13],
        (const float*)d_in[14], (const float*)d_in[15],
        (const float*)d_in[17], (const float*)d_in[19],
        (const float*)d_in[21],
        (const float*)d_in[22], (const float*)d_in[23],
        (char*)d_ws, (float*)d_out);
}

// Round 8
// 1234.977 us; speedup vs baseline: 1.0290x; 1.0290x over previous
//
#include <hip/hip_runtime.h>

typedef unsigned short ushort_t;
typedef unsigned int uint_t;
typedef unsigned long long ull_t;
typedef __attribute__((ext_vector_type(8))) short short8;
typedef __attribute__((ext_vector_type(4))) float f32x4;

#define B_ 1024
#define N_ 64
#define H_ 128
#define NT 256

// bf16 weight-image element offsets
#define IMG_WI 0
#define IMG_WJ 16384
#define IMG_UW 32768
#define IMG_GS 49152
#define IMG_FT 65536
#define IMG_FB 81920
#define IMG_C1 98304
#define IMG_C2 163840
#define IMG_GMT 229376
#define IMG_RW 245760
#define IMG_L 249856
#define IMG_FO 999424

__device__ __forceinline__ ushort_t f2bf(float f) {
    // native RNE f32->bf16; bit-identical to the integer RNE sequence.
    return __builtin_bit_cast(ushort_t, (__bf16)f);
}
__device__ __forceinline__ float bf2f(ushort_t u) {
    union { uint_t i; float f; } v; v.i = ((uint_t)u) << 16; return v.f;
}
__device__ __forceinline__ float siluf(float x) { return x / (1.0f + __expf(-x)); }

// LDS swizzle: 16B-chunk c of row m stored at chunk c ^ (m&7)
__device__ __forceinline__ int sidx(int m, int k) {
    return m * H_ + (((k >> 3) ^ (m & 7)) << 3) + (k & 7);
}
__device__ __forceinline__ int fragoff(int m, int ch) {
    return m * H_ + ((ch ^ (m & 7)) << 3);
}

// ========== preamble: f32 weights -> transposed bf16 images ==============
// LDS 128x32 tile transpose. Reads coalesced (32x4B rows), writes
// vectorized 2x16B per thread.
extern "C" __global__ __launch_bounds__(256)
void convert_weights(const float* __restrict__ msg_W, const float* __restrict__ upd_W,
                     const float* __restrict__ gself_W, const float* __restrict__ fus_W,
                     const float* __restrict__ cb_W1, const float* __restrict__ cb_W2,
                     const float* __restrict__ gmean_W, const float* __restrict__ fo_W1,
                     ushort_t* __restrict__ wimg)
{
    __shared__ ushort_t tile[128][34];
    const int g = blockIdx.x;
    const int tid = threadIdx.x;
    const float* W; int ld = 128, k0 = 0, c0; ushort_t* dst;
    if (g >= 244) {
        int st = g - 244;
        W = fo_W1; c0 = st * 32; dst = wimg + IMG_FO + st * 4096;
    } else {
        const int l = g / 61, r = g - l * 61;
        ushort_t* base = wimg + l * IMG_L;
        if (r == 60) {                   // rW pad image: 4 sub-stages [32f][32k]
            const float* Wr = msg_W + l * 35328 + 256 * 128;
            ushort_t* drw = base + IMG_RW;
            for (int e = 0; e < 16; ++e) {
                int q = threadIdx.x * 16 + e;
                int sub = q >> 10, n = (q >> 5) & 31, k = q & 31;
                drw[q] = f2bf(k < 20 ? Wr[(size_t)k * 128 + sub * 32 + n] : 0.0f);
            }
            return;
        }
        int off, st;
        if      (r < 4)  { W = msg_W + l * 35328;            st = r;      off = IMG_WI;  c0 = st * 32; }
        else if (r < 8)  { W = msg_W + l * 35328;  k0 = 128; st = r - 4;  off = IMG_WJ;  c0 = st * 32; }
        else if (r < 12) { W = upd_W + l * 16384;            st = r - 8;  off = IMG_UW;  c0 = st * 32; }
        else if (r < 16) { W = gself_W + l * 16384;          st = r - 12; off = IMG_GS;  c0 = st * 32; }
        else if (r < 20) { W = fus_W + l * 32768;            st = r - 16; off = IMG_FT;  c0 = st * 32; }
        else if (r < 24) { W = fus_W + l * 32768;  k0 = 128; st = r - 20; off = IMG_FB;  c0 = st * 32; }
        else if (r < 40) { W = cb_W1 + l * 65536;  ld = 512; st = r - 24; off = IMG_C1;  c0 = st * 32; }
        else if (r < 56) { int j = (r - 40) >> 2; W = cb_W2 + l * 65536; k0 = j * 128;
                           st = r - 40; off = IMG_C2; c0 = ((r - 40) & 3) * 32; }
        else             { W = gmean_W + l * 16384;          st = r - 56; off = IMG_GMT; c0 = st * 32; }
        dst = base + off + st * 4096;
    }
    const int kr = tid >> 5, n = tid & 31;
    #pragma unroll
    for (int p = 0; p < 16; ++p) {
        int k = p * 8 + kr;
        tile[k][n] = f2bf(W[(size_t)(k0 + k) * ld + c0 + n]);
    }
    __syncthreads();
    {
        int n2 = tid >> 3, kk = (tid & 7) << 4;
        short8 v0, v1;
        #pragma unroll
        for (int e = 0; e < 8; ++e) v0[e] = (short)tile[kk + e][n2];
        #pragma unroll
        for (int e = 0; e < 8; ++e) v1[e] = (short)tile[kk + 8 + e][n2];
        *(short8*)(dst + n2 * 128 + kk) = v0;
        *(short8*)(dst + n2 * 128 + kk + 8) = v1;
    }
}

// ========== main fused kernel ==============================================
// R5 structure (best: 1197us) + two latency cuts at fixed occupancy:
//  (1) RW image staged in LDS per layer: D's 16 serial g-iters reloaded the
//      SAME 8 B-frags from global L2 (~200cy) each iter; now ds_read_b128
//      (~50cy, conflict-free: wave spans 1024 contiguous bytes). Register
//      hoist of these (R4) spilled at the 128-reg cap; LDS is the right home.
//  (2) Barriers 4->2 per layer with ZERO added work (unlike R6's failed MFMA
//      rewrite): hmean average folded into the GEMV (bit-identical order),
//      GEMV moved after S1 overlapped with D.
// Occupancy is register-pinned at 2 waves/SIMD (gfx950 unified VGPR+AGPR:
// uncapped demand >256 total -> (NT,2)'s 256 cap is binding; LDS is NOT the
// constraint -- R7 proved 53KB didn't unlock a 3rd block). LDS 69632 -> 2
// blocks/CU unchanged.
struct __align__(16) Smem {
    ushort_t T1[N_ * H_];   // 16384B  scratch image (Gm/msum/glob/xhat)
    ushort_t T2[N_ * H_];   // 16384B  scratch image (hj/local/C1)
    ushort_t T3[N_ * H_];   // 16384B  layer-input h image
    float d[1024];          //  4096B
    float env[1024];        //  4096B
    ushort_t idx[1024];     //  2048B
    ushort_t rw[4096];      //  8192B  per-layer staged RW image
    char u[2048];           // spos(768) | part bf16[512](1024B) | gvec f32[128]@1536
};

// one output stage s (16 cols, col = s*16+l15), K=128: 4 B-frags from global
__device__ __forceinline__ f32x4 gemm_s(const short8 a[4], const ushort_t* __restrict__ img,
                                        int s, int l15, int quad)
{
    const ushort_t* base = img + ((s >> 1) << 12) + ((((s & 1) << 4) + l15) << 7) + quad * 8;
    short8 b0 = *(const short8*)(base);
    short8 b1 = *(const short8*)(base + 32);
    short8 b2 = *(const short8*)(base + 64);
    short8 b3 = *(const short8*)(base + 96);
    f32x4 c = {0.f, 0.f, 0.f, 0.f};
    c = __builtin_amdgcn_mfma_f32_16x16x32_bf16(a[0], b0, c, 0, 0, 0);
    c = __builtin_amdgcn_mfma_f32_16x16x32_bf16(a[1], b1, c, 0, 0, 0);
    c = __builtin_amdgcn_mfma_f32_16x16x32_bf16(a[2], b2, c, 0, 0, 0);
    c = __builtin_amdgcn_mfma_f32_16x16x32_bf16(a[3], b3, c, 0, 0, 0);
    return c;
}
__device__ __forceinline__ f32x4 gemm_s_acc(const short8 a[4], const ushort_t* __restrict__ img,
                                            int s, int l15, int quad, f32x4 c)
{
    const ushort_t* base = img + ((s >> 1) << 12) + ((((s & 1) << 4) + l15) << 7) + quad * 8;
    short8 b0 = *(const short8*)(base);
    short8 b1 = *(const short8*)(base + 32);
    short8 b2 = *(const short8*)(base + 64);
    short8 b3 = *(const short8*)(base + 96);
    c = __builtin_amdgcn_mfma_f32_16x16x32_bf16(a[0], b0, c, 0, 0, 0);
    c = __builtin_amdgcn_mfma_f32_16x16x32_bf16(a[1], b1, c, 0, 0, 0);
    c = __builtin_amdgcn_mfma_f32_16x16x32_bf16(a[2], b2, c, 0, 0, 0);
    c = __builtin_amdgcn_mfma_f32_16x16x32_bf16(a[3], b3, c, 0, 0, 0);
    return c;
}
__device__ __forceinline__ void loadA(const ushort_t* __restrict__ X, int mrow, int quad, short8 a[4]) {
    #pragma unroll
    for (int kc = 0; kc < 4; ++kc) a[kc] = *(const short8*)&X[fragoff(mrow, kc * 4 + quad)];
}

extern "C" __global__ __launch_bounds__(NT, 2)
void md17_fused_kernel(
    const float* __restrict__ positions, const int* __restrict__ atomic_numbers,
    const float* __restrict__ atom_embed, const float* __restrict__ pos_W,
    const float* __restrict__ pos_b,
    const float* __restrict__ msg_b, const float* __restrict__ upd_b,
    const float* __restrict__ g_b, const float* __restrict__ fus_b,
    const float* __restrict__ ln_g, const float* __restrict__ ln_b,
    const float* __restrict__ cb_b1, const float* __restrict__ cb_b2,
    const float* __restrict__ fo_b1,
    const float* __restrict__ fo_W2, const float* __restrict__ fo_b2,
    char* __restrict__ ws, float* __restrict__ out)
{
    __shared__ Smem sm;
    const int b = blockIdx.x;
    const int tid = threadIdx.x;
    const int wave = tid >> 6, lane = tid & 63;
    const int quad = lane >> 4, l15 = lane & 15;
    const int mrow = wave * 16 + l15;       // A-frag row (wave-owned)
    const int rbase = wave * 16 + quad * 4; // C-tile row base (wave-owned)

    const ushort_t* wimg = (const ushort_t*)ws;
    float* spos = (float*)sm.u;             // pre-loop only (aliases part)
    ushort_t* part = (ushort_t*)sm.u;       // [4][128] bf16 hmean partials
    float* gvec  = (float*)(sm.u + 1536);

    // residual stream, C-frag layout: hreg[s][r] = h[rbase+r][s*16+l15]
    float hreg[8][4];

    // ---- setup: positions -> LDS ----
    if (tid < 192) spos[tid] = positions[b * 192 + tid];
    __syncthreads();

    // ---- quad-parallel inline kNN: 16-lane group per atom ----
    {
        // candidates: lane owns atoms l15*4 .. l15*4+3 (lane order = index order)
        float cx[4], cy[4], cz[4];
        #pragma unroll
        for (int j = 0; j < 4; ++j) {
            cx[j] = spos[(l15 * 4 + j) * 3 + 0];
            cy[j] = spos[(l15 * 4 + j) * 3 + 1];
            cz[j] = spos[(l15 * 4 + j) * 3 + 2];
        }
        #pragma unroll 1
        for (int it = 0; it < 4; ++it) {
            const int n = wave * 16 + it * 4 + quad;   // this quad-group's atom
            float nx = spos[n * 3 + 0], ny = spos[n * 3 + 1], nz = spos[n * 3 + 2];
            float d2[4];
            #pragma unroll
            for (int j = 0; j < 4; ++j) {
                float dx = __fsub_rn(nx, cx[j]);
                float dy = __fsub_rn(ny, cy[j]);
                float dz = __fsub_rn(nz, cz[j]);
                d2[j] = __fadd_rn(__fadd_rn(__fmul_rn(dx, dx), __fmul_rn(dy, dy)),
                                  __fmul_rn(dz, dz));
                if (l15 * 4 + j == n) d2[j] = 1e30f;   // exclude self
            }
            #pragma unroll 1
            for (int k = 0; k < 16; ++k) {
                // strict < keeps lowest j on intra-lane ties
                float lm = d2[0];
                if (d2[1] < lm) lm = d2[1];
                if (d2[2] < lm) lm = d2[2];
                if (d2[3] < lm) lm = d2[3];
                float gm = lm;
                #pragma unroll
                for (int o = 1; o < 16; o <<= 1) gm = fminf(gm, __shfl_xor(gm, o));
                ull_t bal = __ballot(lm == gm);
                int wl = __ffsll((bal >> (quad * 16)) & 0xFFFFull) - 1;  // lowest lane
                if (l15 == wl) {
                    int jstar = 3;                      // lowest matching slot
                    if (d2[2] == gm) jstar = 2;
                    if (d2[1] == gm) jstar = 1;
                    if (d2[0] == gm) jstar = 0;
                    #pragma unroll
                    for (int j = 0; j < 4; ++j) if (j == jstar) d2[j] = 1e30f;
                    float dd = sqrtf(fmaxf(gm, 1e-12f));
                    sm.d[n * 16 + k] = dd;
                    sm.env[n * 16 + k] = (dd < 5.0f)
                        ? 0.5f * (__cosf(0.62831853071795864769f * dd) + 1.0f) : 0.0f;
                    sm.idx[n * 16 + k] = (ushort_t)(wl * 4 + jstar);
                }
            }
        }
    }

    // ---- embeddings, per-lane into hreg + T3 image ----
    {
        int an[4];
        #pragma unroll
        for (int r = 0; r < 4; ++r) an[r] = atomic_numbers[b * N_ + rbase + r];
        #pragma unroll
        for (int s = 0; s < 8; ++s) {
            int col = s * 16 + l15;
            #pragma unroll
            for (int r = 0; r < 4; ++r) {
                float v;
                if (s < 2) {                        // col < 32: atom-type embed
                    v = atom_embed[an[r] * 32 + col];
                } else {                            // col >= 32: position MLP
                    int j = col - 32;
                    v = pos_b[j];
                    #pragma unroll
                    for (int c = 0; c < 3; ++c)
                        v = fmaf(spos[(rbase + r) * 3 + c], pos_W[c * 96 + j], v);
                }
                hreg[s][r] = v;
                sm.T3[sidx(rbase + r, col)] = f2bf(v);
            }
        }
    }
    __syncthreads();    // spos reads done; part (alias) written below
    // layer-0 hmean partials
    #pragma unroll
    for (int s = 0; s < 8; ++s) {
        int col = s * 16 + l15;
        float p = hreg[s][0] + hreg[s][1] + hreg[s][2] + hreg[s][3];
        p += __shfl_xor(p, 16);
        p += __shfl_xor(p, 32);
        if (quad == 0) part[wave * 128 + col] = f2bf(p);
    }

    #pragma unroll 1
    for (int l = 0; l < 4; ++l) {
        const ushort_t* wl = wimg + l * IMG_L;
        const float* mb  = msg_b + l * H_;
        const float* ub  = upd_b + l * H_;
        const float* gb  = g_b + l * H_;
        const float* fb  = fus_b + l * H_;
        const float* lg  = ln_g + l * H_;
        const float* lb  = ln_b + l * H_;
        const float* c1b = cb_b1 + l * 4 * H_;
        const float* c2b = cb_b2 + l * H_;

        // C: stage RW -> LDS ; a_h from T3 ; WI -> T1 (+mb) ; WJ -> T2
        {
            const ushort_t* src = wl + IMG_RW;
            *(short8*)&sm.rw[tid * 16]     = *(const short8*)(src + tid * 16);
            *(short8*)&sm.rw[tid * 16 + 8] = *(const short8*)(src + tid * 16 + 8);
        }
        {
            short8 a_h[4]; loadA(sm.T3, mrow, quad, a_h);
            #pragma unroll 2
            for (int s = 0; s < 8; ++s) {
                f32x4 c = gemm_s(a_h, wl + IMG_WI, s, l15, quad);
                int col = s * 16 + l15; float bv = mb[col];
                #pragma unroll
                for (int r = 0; r < 4; ++r)
                    sm.T1[sidx(rbase + r, col)] = f2bf(c[r] + bv);
            }
            #pragma unroll 2
            for (int s = 0; s < 8; ++s) {
                f32x4 c = gemm_s(a_h, wl + IMG_WJ, s, l15, quad);
                int col = s * 16 + l15;
                #pragma unroll
                for (int r = 0; r < 4; ++r)
                    sm.T2[sidx(rbase + r, col)] = f2bf(c[r]);
            }
        }
        __syncthreads();                                 // S1 (part, rw, T2 visible)

        // gvec GEMV (tid<128), hmean average folded in; overlapped with D
        if (tid < H_) {
            float s = gb[tid];
            const ushort_t* wrow = wl + IMG_GMT + tid * 128;
            for (int c = 0; c < 128; c += 8) {
                short8 w = *(const short8*)(wrow + c);
                #pragma unroll
                for (int i = 0; i < 8; ++i) {
                    float hm = (bf2f(part[c + i]) + bf2f(part[128 + c + i])
                              + bf2f(part[256 + c + i]) + bf2f(part[384 + c + i]))
                              * (1.0f / 64.0f);
                    s = fmaf(hm, bf2f((ushort_t)w[i]), s);
                }
            }
            gvec[tid] = s;
        }

        // D: msum — whole wave per atom n = wave*16+g (own rows), in place in T1
        {
            float ccv[8];
            #pragma unroll
            for (int j = 0; j < 8; ++j)
                ccv[j] = (float)((double)(quad * 8 + j) * (5.0 / 19.0));
            #pragma unroll 1
            for (int g = 0; g < 16; ++g) {
                int n = wave * 16 + g;
                int jv[4]; float ev[4];
                #pragma unroll
                for (int r = 0; r < 4; ++r) {
                    int k = quad * 4 + r;
                    jv[r] = sm.idx[n * 16 + k];
                    ev[r] = sm.env[n * 16 + k];
                }
                float ddm = sm.d[n * 16 + l15];
                short8 arb;
                #pragma unroll
                for (int j = 0; j < 8; ++j) {
                    float t2 = ddm - ccv[j];
                    float rv = __expf(-10.0f * t2 * t2);
                    arb[j] = (short)((quad * 8 + j) < 20 ? f2bf(rv) : (ushort_t)0);
                }
                #pragma unroll
                for (int s = 0; s < 8; ++s) {
                    int col = s * 16 + l15;
                    short8 brw = *(const short8*)&sm.rw[((s >> 1) << 10)
                                            + ((((s & 1) << 4) + l15) << 5) + quad * 8];
                    f32x4 c = {0.f, 0.f, 0.f, 0.f};
                    c = __builtin_amdgcn_mfma_f32_16x16x32_bf16(arb, brw, c, 0, 0, 0);
                    float ai = bf2f(sm.T1[sidx(n, col)]);
                    float acc = 0.f;
                    #pragma unroll
                    for (int r = 0; r < 4; ++r) {
                        float gm = bf2f(sm.T2[sidx(jv[r], col)]);
                        acc = fmaf(siluf(ai + gm + c[r]), ev[r], acc);
                    }
                    acc += __shfl_xor(acc, 16);
                    acc += __shfl_xor(acc, 32);
                    if (quad == 0) sm.T1[sidx(n, col)] = f2bf(acc);
                }
            }
        }
        __syncthreads();                                 // S2 (Gm reads done; T2 free)

        // ---- free-run region: everything below touches only own rows ----

        // F: UW(a_m)+hreg -> T2 local ; GS(a_h reloaded from T3) + gvec -> T1 glob
        {
            short8 a_m[4]; loadA(sm.T1, mrow, quad, a_m);
            #pragma unroll
            for (int s = 0; s < 8; ++s) {
                f32x4 c = gemm_s(a_m, wl + IMG_UW, s, l15, quad);
                int col = s * 16 + l15; float bv = ub[col];
                #pragma unroll
                for (int r = 0; r < 4; ++r)
                    sm.T2[sidx(rbase + r, col)] = f2bf(hreg[s][r] + siluf(c[r] + bv));
            }
            short8 a_h[4]; loadA(sm.T3, mrow, quad, a_h);
            #pragma unroll 2
            for (int s = 0; s < 8; ++s) {
                f32x4 c = gemm_s(a_h, wl + IMG_GS, s, l15, quad);
                int col = s * 16 + l15; float gv = gvec[col];
                #pragma unroll
                for (int r = 0; r < 4; ++r)
                    sm.T1[sidx(rbase + r, col)] = f2bf(siluf(c[r] + gv));
            }
        }

        // G: fused = silu([local|glob]@[FT;FB]+fb) -> hreg ; LN sums in regs
        float sr[4] = {0.f, 0.f, 0.f, 0.f}, qr[4] = {0.f, 0.f, 0.f, 0.f};
        {
            short8 a_t[4];
            loadA(sm.T2, mrow, quad, a_t);               // local
            #pragma unroll
            for (int s = 0; s < 8; ++s) {
                f32x4 c = gemm_s(a_t, wl + IMG_FT, s, l15, quad);
                #pragma unroll
                for (int r = 0; r < 4; ++r) hreg[s][r] = c[r];  // residual h is dead here
            }
            loadA(sm.T1, mrow, quad, a_t);               // glob
            #pragma unroll
            for (int s = 0; s < 8; ++s) {
                f32x4 c = gemm_s(a_t, wl + IMG_FB, s, l15, quad);
                int col = s * 16 + l15; float bv = fb[col];
                #pragma unroll
                for (int r = 0; r < 4; ++r) {
                    float v = siluf(hreg[s][r] + c[r] + bv);
                    hreg[s][r] = v;
                    sr[r] += v; qr[r] += v * v;
                }
            }
            #pragma unroll
            for (int o = 1; o < 16; o <<= 1) {
                #pragma unroll
                for (int r = 0; r < 4; ++r) {
                    sr[r] += __shfl_xor(sr[r], o);
                    qr[r] += __shfl_xor(qr[r], o);
                }
            }
        }

        // H: LN normalize (wave-local) -> T1 (x-hat)
        #pragma unroll
        for (int r = 0; r < 4; ++r) {
            float mu = sr[r] * (1.0f / 128.0f);
            float var = qr[r] * (1.0f / 128.0f) - mu * mu;
            float rs = rsqrtf(var + 1e-5f);
            int row = rbase + r;
            #pragma unroll
            for (int s = 0; s < 8; ++s) {
                int col = s * 16 + l15;
                sm.T1[sidx(row, col)] = f2bf((hreg[s][r] - mu) * rs * lg[col] + lb[col]);
            }
        }

        // J: Clifford MLP, 4 K-chunks; C1 -> T2; C2 accumulates into acc2.
        // acc2 SEEDED with residual + c2b (hreg dead across j-loop); a_x
        // reloaded from T1 each chunk.
        {
            f32x4 acc2[8];
            #pragma unroll
            for (int s = 0; s < 8; ++s) {
                int col = s * 16 + l15; float bv = c2b[col];
                #pragma unroll
                for (int r = 0; r < 4; ++r) acc2[s][r] = hreg[s][r] + bv;
            }
            #pragma unroll 1
            for (int j = 0; j < 4; ++j) {
                short8 a_x[4]; loadA(sm.T1, mrow, quad, a_x);
                #pragma unroll 2
                for (int s = 0; s < 8; ++s) {
                    f32x4 c = gemm_s(a_x, wl + IMG_C1 + j * 16384, s, l15, quad);
                    int col = s * 16 + l15; float bv = c1b[j * H_ + col];
                    #pragma unroll
                    for (int r = 0; r < 4; ++r)
                        sm.T2[sidx(rbase + r, col)] = f2bf(siluf(c[r] + bv));
                }
                short8 a_t[4]; loadA(sm.T2, mrow, quad, a_t);
                #pragma unroll
                for (int s = 0; s < 8; ++s)
                    acc2[s] = gemm_s_acc(a_t, wl + IMG_C2 + j * 16384, s, l15, quad, acc2[s]);
            }
            // K: h_next = acc2 -> hreg + T3 image ; fold next-layer hmean partials
            #pragma unroll
            for (int s = 0; s < 8; ++s) {
                int col = s * 16 + l15;
                float p = 0.f;
                #pragma unroll
                for (int r = 0; r < 4; ++r) {
                    float v = acc2[s][r];
                    hreg[s][r] = v;
                    sm.T3[sidx(rbase + r, col)] = f2bf(v);
                    p += v;
                }
                p += __shfl_xor(p, 16);
                p += __shfl_xor(p, 32);
                if (quad == 0) part[wave * 128 + col] = f2bf(p);
            }
        }
        // no layer-end barrier: next C touches only own rows + rw (no readers
        // until after next S1); part read only after next S1.
    }

    // ---- head: FO -> T2 (own rows, no barrier) ; barrier ; gather -> out ----
    {
        short8 a_f[4]; loadA(sm.T3, mrow, quad, a_f);
        #pragma unroll 2
        for (int s = 0; s < 8; ++s) {
            f32x4 c = gemm_s(a_f, wimg + IMG_FO, s, l15, quad);
            int col = s * 16 + l15; float bv = fo_b1[col];
            #pragma unroll
            for (int r = 0; r < 4; ++r)
                sm.T2[sidx(rbase + r, col)] = f2bf(siluf(c[r] + bv));
        }
    }
    __syncthreads();
    if (tid < 192) {
        int n = tid / 3, j = tid - n * 3;
        float s = fo_b2[j];
        #pragma unroll 1
        for (int ch = 0; ch < 16; ++ch) {
            short8 v = *(const short8*)&sm.T2[fragoff(n, ch)];
            #pragma unroll
            for (int i = 0; i < 8; ++i)
                s = fmaf(bf2f((ushort_t)v[i]), fo_W2[(ch * 8 + i) * 3 + j], s);
        }
        out[b * 192 + tid] = s;
    }
}

extern "C" void kernel_launch(void* const* d_in, const int* in_sizes, int n_in,
                              void* d_out, int out_size, void* d_ws, size_t ws_size,
                              hipStream_t stream) {
    (void)in_sizes; (void)n_in; (void)out_size; (void)ws_size;
    convert_weights<<<248, 256, 0, stream>>>(
        (const float*)d_in[5], (const float*)d_in[7], (const float*)d_in[9],
        (const float*)d_in[12], (const float*)d_in[16], (const float*)d_in[18],
        (const float*)d_in[10], (const float*)d_in[20], (ushort_t*)d_ws);
    md17_fused_kernel<<<B_, NT, 0, stream>>>(
        (const float*)d_in[0], (const int*)d_in[1],
        (const float*)d_in[2], (const float*)d_in[3], (const float*)d_in[4],
        (const float*)d_in[6], (const float*)d_in[8],
        (const float*)d_in[11], (const float*)d_in[13],
        (const float*)d_in[14], (const float*)d_in[15],
        (const float*)d_in[17], (const float*)d_in[19],
        (const float*)d_in[21],
        (const float*)d_in[22], (const float*)d_in[23],
        (char*)d_ws, (float*)d_out);
}

// Round 9
// 1219.755 us; speedup vs baseline: 1.0418x; 1.0125x over previous
//
#include <hip/hip_runtime.h>

typedef unsigned short ushort_t;
typedef unsigned int uint_t;
typedef unsigned long long ull_t;
typedef __attribute__((ext_vector_type(8))) short short8;
typedef __attribute__((ext_vector_type(4))) float f32x4;

#define B_ 1024
#define N_ 64
#define H_ 128
#define NT 256

// bf16 weight-image element offsets
#define IMG_WI 0
#define IMG_WJ 16384
#define IMG_UW 32768
#define IMG_GS 49152
#define IMG_FT 65536
#define IMG_FB 81920
#define IMG_C1 98304
#define IMG_C2 163840
#define IMG_GMT 229376
#define IMG_RW 245760
#define IMG_L 249856
#define IMG_FO 999424

__device__ __forceinline__ ushort_t f2bf(float f) {
    // native RNE f32->bf16; bit-identical to the integer RNE sequence.
    return __builtin_bit_cast(ushort_t, (__bf16)f);
}
__device__ __forceinline__ float bf2f(ushort_t u) {
    union { uint_t i; float f; } v; v.i = ((uint_t)u) << 16; return v.f;
}
__device__ __forceinline__ float siluf(float x) { return x / (1.0f + __expf(-x)); }

// LDS swizzle: 16B-chunk c of row m stored at chunk c ^ (m&7)
__device__ __forceinline__ int sidx(int m, int k) {
    return m * H_ + (((k >> 3) ^ (m & 7)) << 3) + (k & 7);
}
__device__ __forceinline__ int fragoff(int m, int ch) {
    return m * H_ + ((ch ^ (m & 7)) << 3);
}

// ========== preamble: f32 weights -> transposed bf16 images ==============
// LDS 128x32 tile transpose. Reads coalesced (32x4B rows), writes
// vectorized 2x16B per thread.
extern "C" __global__ __launch_bounds__(256)
void convert_weights(const float* __restrict__ msg_W, const float* __restrict__ upd_W,
                     const float* __restrict__ gself_W, const float* __restrict__ fus_W,
                     const float* __restrict__ cb_W1, const float* __restrict__ cb_W2,
                     const float* __restrict__ gmean_W, const float* __restrict__ fo_W1,
                     ushort_t* __restrict__ wimg)
{
    __shared__ ushort_t tile[128][34];
    const int g = blockIdx.x;
    const int tid = threadIdx.x;
    const float* W; int ld = 128, k0 = 0, c0; ushort_t* dst;
    if (g >= 244) {
        int st = g - 244;
        W = fo_W1; c0 = st * 32; dst = wimg + IMG_FO + st * 4096;
    } else {
        const int l = g / 61, r = g - l * 61;
        ushort_t* base = wimg + l * IMG_L;
        if (r == 60) {                   // rW pad image: 4 sub-stages [32f][32k]
            const float* Wr = msg_W + l * 35328 + 256 * 128;
            ushort_t* drw = base + IMG_RW;
            for (int e = 0; e < 16; ++e) {
                int q = threadIdx.x * 16 + e;
                int sub = q >> 10, n = (q >> 5) & 31, k = q & 31;
                drw[q] = f2bf(k < 20 ? Wr[(size_t)k * 128 + sub * 32 + n] : 0.0f);
            }
            return;
        }
        int off, st;
        if      (r < 4)  { W = msg_W + l * 35328;            st = r;      off = IMG_WI;  c0 = st * 32; }
        else if (r < 8)  { W = msg_W + l * 35328;  k0 = 128; st = r - 4;  off = IMG_WJ;  c0 = st * 32; }
        else if (r < 12) { W = upd_W + l * 16384;            st = r - 8;  off = IMG_UW;  c0 = st * 32; }
        else if (r < 16) { W = gself_W + l * 16384;          st = r - 12; off = IMG_GS;  c0 = st * 32; }
        else if (r < 20) { W = fus_W + l * 32768;            st = r - 16; off = IMG_FT;  c0 = st * 32; }
        else if (r < 24) { W = fus_W + l * 32768;  k0 = 128; st = r - 20; off = IMG_FB;  c0 = st * 32; }
        else if (r < 40) { W = cb_W1 + l * 65536;  ld = 512; st = r - 24; off = IMG_C1;  c0 = st * 32; }
        else if (r < 56) { int j = (r - 40) >> 2; W = cb_W2 + l * 65536; k0 = j * 128;
                           st = r - 40; off = IMG_C2; c0 = ((r - 40) & 3) * 32; }
        else             { W = gmean_W + l * 16384;          st = r - 56; off = IMG_GMT; c0 = st * 32; }
        dst = base + off + st * 4096;
    }
    const int kr = tid >> 5, n = tid & 31;
    #pragma unroll
    for (int p = 0; p < 16; ++p) {
        int k = p * 8 + kr;
        tile[k][n] = f2bf(W[(size_t)(k0 + k) * ld + c0 + n]);
    }
    __syncthreads();
    {
        int n2 = tid >> 3, kk = (tid & 7) << 4;
        short8 v0, v1;
        #pragma unroll
        for (int e = 0; e < 8; ++e) v0[e] = (short)tile[kk + e][n2];
        #pragma unroll
        for (int e = 0; e < 8; ++e) v1[e] = (short)tile[kk + 8 + e][n2];
        *(short8*)(dst + n2 * 128 + kk) = v0;
        *(short8*)(dst + n2 * 128 + kk + 8) = v1;
    }
}

// ========== main fused kernel ==============================================
// Exact R5 structure (best: 1197us) + two isolated diffs:
//  (a) B2 deleted; GEMV moved after B3 (unchanged code): B3 provides the
//      hmean write->read ordering, and the GEMV overlaps D instead of
//      sitting serially between barriers. 3 barriers/layer.
//  (b) J double-buffered: C1 scratch alternates T2 (j even) / T3 (j odd --
//      T3's h-image is dead during J: F consumed it, K rewrites it), with
//      #pragma unroll 2 so j+1's C1 MFMAs fill j's C2 LDS-turnaround stall.
// NOT repeated from R6-R8 failures: no GMT-MFMA rewrite, no rw LDS staging
// (8KB image is L1-resident; staging added 8.6M bank conflicts), no folded
// hmean in GEMV, no d/env recompute. Occupancy is register-pinned at
// 2 waves/SIMD (gfx950 unified VGPR+AGPR file; uncapped demand > 256/wave).
struct __align__(16) Smem {
    ushort_t T1[N_ * H_];   // 16384B  scratch image (Gm/msum/glob/xhat)
    ushort_t T2[N_ * H_];   // 16384B  scratch image (hj/local/C1 even)
    ushort_t T3[N_ * H_];   // 16384B  layer-input h image (C1-odd scratch in J)
    float d[1024];          //  4096B
    float env[1024];        //  4096B
    ushort_t idx[1024];     //  2048B
    char u[2048];           // spos(768) | part bf16[512] | hmean@1024 | gvec@1536
};

// one output stage s (16 cols, col = s*16+l15), K=128: 4 B-frags from global
__device__ __forceinline__ f32x4 gemm_s(const short8 a[4], const ushort_t* __restrict__ img,
                                        int s, int l15, int quad)
{
    const ushort_t* base = img + ((s >> 1) << 12) + ((((s & 1) << 4) + l15) << 7) + quad * 8;
    short8 b0 = *(const short8*)(base);
    short8 b1 = *(const short8*)(base + 32);
    short8 b2 = *(const short8*)(base + 64);
    short8 b3 = *(const short8*)(base + 96);
    f32x4 c = {0.f, 0.f, 0.f, 0.f};
    c = __builtin_amdgcn_mfma_f32_16x16x32_bf16(a[0], b0, c, 0, 0, 0);
    c = __builtin_amdgcn_mfma_f32_16x16x32_bf16(a[1], b1, c, 0, 0, 0);
    c = __builtin_amdgcn_mfma_f32_16x16x32_bf16(a[2], b2, c, 0, 0, 0);
    c = __builtin_amdgcn_mfma_f32_16x16x32_bf16(a[3], b3, c, 0, 0, 0);
    return c;
}
__device__ __forceinline__ f32x4 gemm_s_acc(const short8 a[4], const ushort_t* __restrict__ img,
                                            int s, int l15, int quad, f32x4 c)
{
    const ushort_t* base = img + ((s >> 1) << 12) + ((((s & 1) << 4) + l15) << 7) + quad * 8;
    short8 b0 = *(const short8*)(base);
    short8 b1 = *(const short8*)(base + 32);
    short8 b2 = *(const short8*)(base + 64);
    short8 b3 = *(const short8*)(base + 96);
    c = __builtin_amdgcn_mfma_f32_16x16x32_bf16(a[0], b0, c, 0, 0, 0);
    c = __builtin_amdgcn_mfma_f32_16x16x32_bf16(a[1], b1, c, 0, 0, 0);
    c = __builtin_amdgcn_mfma_f32_16x16x32_bf16(a[2], b2, c, 0, 0, 0);
    c = __builtin_amdgcn_mfma_f32_16x16x32_bf16(a[3], b3, c, 0, 0, 0);
    return c;
}
__device__ __forceinline__ void loadA(const ushort_t* __restrict__ X, int mrow, int quad, short8 a[4]) {
    #pragma unroll
    for (int kc = 0; kc < 4; ++kc) a[kc] = *(const short8*)&X[fragoff(mrow, kc * 4 + quad)];
}

extern "C" __global__ __launch_bounds__(NT, 2)
void md17_fused_kernel(
    const float* __restrict__ positions, const int* __restrict__ atomic_numbers,
    const float* __restrict__ atom_embed, const float* __restrict__ pos_W,
    const float* __restrict__ pos_b,
    const float* __restrict__ msg_b, const float* __restrict__ upd_b,
    const float* __restrict__ g_b, const float* __restrict__ fus_b,
    const float* __restrict__ ln_g, const float* __restrict__ ln_b,
    const float* __restrict__ cb_b1, const float* __restrict__ cb_b2,
    const float* __restrict__ fo_b1,
    const float* __restrict__ fo_W2, const float* __restrict__ fo_b2,
    char* __restrict__ ws, float* __restrict__ out)
{
    __shared__ Smem sm;
    const int b = blockIdx.x;
    const int tid = threadIdx.x;
    const int wave = tid >> 6, lane = tid & 63;
    const int quad = lane >> 4, l15 = lane & 15;
    const int mrow = wave * 16 + l15;       // A-frag row (wave-owned)
    const int rbase = wave * 16 + quad * 4; // C-tile row base (wave-owned)

    const ushort_t* wimg = (const ushort_t*)ws;
    float* spos = (float*)sm.u;
    ushort_t* part = (ushort_t*)sm.u;       // [4][128] bf16 hmean partials
    float* hmean = (float*)(sm.u + 1024);
    float* gvec  = (float*)(sm.u + 1536);

    // residual stream, C-frag layout: hreg[s][r] = h[rbase+r][s*16+l15]
    float hreg[8][4];

    // ---- setup: positions -> LDS ----
    if (tid < 192) spos[tid] = positions[b * 192 + tid];
    __syncthreads();

    // ---- quad-parallel inline kNN: 16-lane group per atom ----
    {
        // candidates: lane owns atoms l15*4 .. l15*4+3 (lane order = index order)
        float cx[4], cy[4], cz[4];
        #pragma unroll
        for (int j = 0; j < 4; ++j) {
            cx[j] = spos[(l15 * 4 + j) * 3 + 0];
            cy[j] = spos[(l15 * 4 + j) * 3 + 1];
            cz[j] = spos[(l15 * 4 + j) * 3 + 2];
        }
        #pragma unroll 1
        for (int it = 0; it < 4; ++it) {
            const int n = wave * 16 + it * 4 + quad;   // this quad-group's atom
            float nx = spos[n * 3 + 0], ny = spos[n * 3 + 1], nz = spos[n * 3 + 2];
            float d2[4];
            #pragma unroll
            for (int j = 0; j < 4; ++j) {
                float dx = __fsub_rn(nx, cx[j]);
                float dy = __fsub_rn(ny, cy[j]);
                float dz = __fsub_rn(nz, cz[j]);
                d2[j] = __fadd_rn(__fadd_rn(__fmul_rn(dx, dx), __fmul_rn(dy, dy)),
                                  __fmul_rn(dz, dz));
                if (l15 * 4 + j == n) d2[j] = 1e30f;   // exclude self
            }
            #pragma unroll 1
            for (int k = 0; k < 16; ++k) {
                // strict < keeps lowest j on intra-lane ties
                float lm = d2[0];
                if (d2[1] < lm) lm = d2[1];
                if (d2[2] < lm) lm = d2[2];
                if (d2[3] < lm) lm = d2[3];
                float gm = lm;
                #pragma unroll
                for (int o = 1; o < 16; o <<= 1) gm = fminf(gm, __shfl_xor(gm, o));
                ull_t bal = __ballot(lm == gm);
                int wl = __ffsll((bal >> (quad * 16)) & 0xFFFFull) - 1;  // lowest lane
                if (l15 == wl) {
                    int jstar = 3;                      // lowest matching slot
                    if (d2[2] == gm) jstar = 2;
                    if (d2[1] == gm) jstar = 1;
                    if (d2[0] == gm) jstar = 0;
                    #pragma unroll
                    for (int j = 0; j < 4; ++j) if (j == jstar) d2[j] = 1e30f;
                    float dd = sqrtf(fmaxf(gm, 1e-12f));
                    sm.d[n * 16 + k] = dd;
                    sm.env[n * 16 + k] = (dd < 5.0f)
                        ? 0.5f * (__cosf(0.62831853071795864769f * dd) + 1.0f) : 0.0f;
                    sm.idx[n * 16 + k] = (ushort_t)(wl * 4 + jstar);
                }
            }
        }
    }

    // ---- embeddings, per-lane into hreg + T3 image ----
    {
        int an[4];
        #pragma unroll
        for (int r = 0; r < 4; ++r) an[r] = atomic_numbers[b * N_ + rbase + r];
        #pragma unroll
        for (int s = 0; s < 8; ++s) {
            int col = s * 16 + l15;
            #pragma unroll
            for (int r = 0; r < 4; ++r) {
                float v;
                if (s < 2) {                        // col < 32: atom-type embed
                    v = atom_embed[an[r] * 32 + col];
                } else {                            // col >= 32: position MLP
                    int j = col - 32;
                    v = pos_b[j];
                    #pragma unroll
                    for (int c = 0; c < 3; ++c)
                        v = fmaf(spos[(rbase + r) * 3 + c], pos_W[c * 96 + j], v);
                }
                hreg[s][r] = v;
                sm.T3[sidx(rbase + r, col)] = f2bf(v);
            }
        }
    }
    __syncthreads();
    // layer-0 hmean partials (stage A folded out of the loop)
    #pragma unroll
    for (int s = 0; s < 8; ++s) {
        int col = s * 16 + l15;
        float p = hreg[s][0] + hreg[s][1] + hreg[s][2] + hreg[s][3];
        p += __shfl_xor(p, 16);
        p += __shfl_xor(p, 32);
        if (quad == 0) part[wave * 128 + col] = f2bf(p);
    }

    #pragma unroll 1
    for (int l = 0; l < 4; ++l) {
        const ushort_t* wl = wimg + l * IMG_L;
        const float* mb  = msg_b + l * H_;
        const float* ub  = upd_b + l * H_;
        const float* gb  = g_b + l * H_;
        const float* fb  = fus_b + l * H_;
        const float* lg  = ln_g + l * H_;
        const float* lb  = ln_b + l * H_;
        const float* c1b = cb_b1 + l * 4 * H_;
        const float* c2b = cb_b2 + l * H_;

        __syncthreads();                                 // B1 (part, prev-K T3 visible)
        // hmean (tid<128); read only after B3 -> no second barrier needed
        if (tid < H_)
            hmean[tid] = (bf2f(part[tid]) + bf2f(part[128 + tid])
                        + bf2f(part[256 + tid]) + bf2f(part[384 + tid])) * (1.0f / 64.0f);

        // C: a_h from T3 ; WI -> T1 (+mb) ; WJ -> T2
        {
            short8 a_h[4]; loadA(sm.T3, mrow, quad, a_h);
            #pragma unroll 2
            for (int s = 0; s < 8; ++s) {
                f32x4 c = gemm_s(a_h, wl + IMG_WI, s, l15, quad);
                int col = s * 16 + l15; float bv = mb[col];
                #pragma unroll
                for (int r = 0; r < 4; ++r)
                    sm.T1[sidx(rbase + r, col)] = f2bf(c[r] + bv);
            }
            #pragma unroll 2
            for (int s = 0; s < 8; ++s) {
                f32x4 c = gemm_s(a_h, wl + IMG_WJ, s, l15, quad);
                int col = s * 16 + l15;
                #pragma unroll
                for (int r = 0; r < 4; ++r)
                    sm.T2[sidx(rbase + r, col)] = f2bf(c[r]);
            }
        }
        __syncthreads();                                 // B3 (Gm, hmean visible)

        // gvec GEMV (tid<128), overlapped with D; gvec read after B4
        if (tid < H_) {
            float s = gb[tid];
            const ushort_t* wrow = wl + IMG_GMT + tid * 128;
            for (int c = 0; c < 128; c += 8) {
                short8 w = *(const short8*)(wrow + c);
                #pragma unroll
                for (int i = 0; i < 8; ++i) s = fmaf(hmean[c + i], bf2f((ushort_t)w[i]), s);
            }
            gvec[tid] = s;
        }

        // D: msum — whole wave per atom n = wave*16+g (own rows), in place in T1
        {
            float ccv[8];
            #pragma unroll
            for (int j = 0; j < 8; ++j)
                ccv[j] = (float)((double)(quad * 8 + j) * (5.0 / 19.0));
            #pragma unroll 1
            for (int g = 0; g < 16; ++g) {
                int n = wave * 16 + g;
                int jv[4]; float ev[4];
                #pragma unroll
                for (int r = 0; r < 4; ++r) {
                    int k = quad * 4 + r;
                    jv[r] = sm.idx[n * 16 + k];
                    ev[r] = sm.env[n * 16 + k];
                }
                float ddm = sm.d[n * 16 + l15];
                short8 arb;
                #pragma unroll
                for (int j = 0; j < 8; ++j) {
                    float t2 = ddm - ccv[j];
                    float rv = __expf(-10.0f * t2 * t2);
                    arb[j] = (short)((quad * 8 + j) < 20 ? f2bf(rv) : (ushort_t)0);
                }
                #pragma unroll
                for (int s = 0; s < 8; ++s) {
                    int col = s * 16 + l15;
                    const ushort_t* rbase_p = wl + IMG_RW + ((s >> 1) << 10)
                                            + ((((s & 1) << 4) + l15) << 5) + quad * 8;
                    short8 brw = *(const short8*)rbase_p;
                    f32x4 c = {0.f, 0.f, 0.f, 0.f};
                    c = __builtin_amdgcn_mfma_f32_16x16x32_bf16(arb, brw, c, 0, 0, 0);
                    float ai = bf2f(sm.T1[sidx(n, col)]);
                    float acc = 0.f;
                    #pragma unroll
                    for (int r = 0; r < 4; ++r) {
                        float gm = bf2f(sm.T2[sidx(jv[r], col)]);
                        acc = fmaf(siluf(ai + gm + c[r]), ev[r], acc);
                    }
                    acc += __shfl_xor(acc, 16);
                    acc += __shfl_xor(acc, 32);
                    if (quad == 0) sm.T1[sidx(n, col)] = f2bf(acc);
                }
            }
        }
        __syncthreads();                                 // B4 (Gm reads done; gvec ready)

        // ---- free-run region: everything below touches only own rows ----

        // F: UW(a_m)+hreg -> T2 local ; GS(a_h reloaded from T3) + gvec -> T1 glob
        {
            short8 a_m[4]; loadA(sm.T1, mrow, quad, a_m);
            #pragma unroll
            for (int s = 0; s < 8; ++s) {
                f32x4 c = gemm_s(a_m, wl + IMG_UW, s, l15, quad);
                int col = s * 16 + l15; float bv = ub[col];
                #pragma unroll
                for (int r = 0; r < 4; ++r)
                    sm.T2[sidx(rbase + r, col)] = f2bf(hreg[s][r] + siluf(c[r] + bv));
            }
            short8 a_h[4]; loadA(sm.T3, mrow, quad, a_h);
            #pragma unroll 2
            for (int s = 0; s < 8; ++s) {
                f32x4 c = gemm_s(a_h, wl + IMG_GS, s, l15, quad);
                int col = s * 16 + l15; float gv = gvec[col];
                #pragma unroll
                for (int r = 0; r < 4; ++r)
                    sm.T1[sidx(rbase + r, col)] = f2bf(siluf(c[r] + gv));
            }
        }

        // G: fused = silu([local|glob]@[FT;FB]+fb) -> hreg ; LN sums in regs
        float sr[4] = {0.f, 0.f, 0.f, 0.f}, qr[4] = {0.f, 0.f, 0.f, 0.f};
        {
            short8 a_t[4];
            loadA(sm.T2, mrow, quad, a_t);               // local
            #pragma unroll
            for (int s = 0; s < 8; ++s) {
                f32x4 c = gemm_s(a_t, wl + IMG_FT, s, l15, quad);
                #pragma unroll
                for (int r = 0; r < 4; ++r) hreg[s][r] = c[r];  // residual h is dead here
            }
            loadA(sm.T1, mrow, quad, a_t);               // glob
            #pragma unroll
            for (int s = 0; s < 8; ++s) {
                f32x4 c = gemm_s(a_t, wl + IMG_FB, s, l15, quad);
                int col = s * 16 + l15; float bv = fb[col];
                #pragma unroll
                for (int r = 0; r < 4; ++r) {
                    float v = siluf(hreg[s][r] + c[r] + bv);
                    hreg[s][r] = v;
                    sr[r] += v; qr[r] += v * v;
                }
            }
            #pragma unroll
            for (int o = 1; o < 16; o <<= 1) {
                #pragma unroll
                for (int r = 0; r < 4; ++r) {
                    sr[r] += __shfl_xor(sr[r], o);
                    qr[r] += __shfl_xor(qr[r], o);
                }
            }
        }

        // H: LN normalize (wave-local) -> T1 (x-hat)
        #pragma unroll
        for (int r = 0; r < 4; ++r) {
            float mu = sr[r] * (1.0f / 128.0f);
            float var = qr[r] * (1.0f / 128.0f) - mu * mu;
            float rs = rsqrtf(var + 1e-5f);
            int row = rbase + r;
            #pragma unroll
            for (int s = 0; s < 8; ++s) {
                int col = s * 16 + l15;
                sm.T1[sidx(row, col)] = f2bf((hreg[s][r] - mu) * rs * lg[col] + lb[col]);
            }
        }

        // J: Clifford MLP, 4 K-chunks; C1 scratch alternates T2/T3 (T3's h
        // image is dead here: F consumed it, K rewrites it). unroll 2 lets
        // j+1's C1 MFMAs overlap j's C2 LDS turnaround (no WAR on one buffer).
        // acc2 SEEDED with residual + c2b (hreg dead across j-loop).
        {
            f32x4 acc2[8];
            #pragma unroll
            for (int s = 0; s < 8; ++s) {
                int col = s * 16 + l15; float bv = c2b[col];
                #pragma unroll
                for (int r = 0; r < 4; ++r) acc2[s][r] = hreg[s][r] + bv;
            }
            #pragma unroll 2
            for (int j = 0; j < 4; ++j) {
                ushort_t* Cbuf = (j & 1) ? sm.T3 : sm.T2;
                short8 a_x[4]; loadA(sm.T1, mrow, quad, a_x);
                #pragma unroll 2
                for (int s = 0; s < 8; ++s) {
                    f32x4 c = gemm_s(a_x, wl + IMG_C1 + j * 16384, s, l15, quad);
                    int col = s * 16 + l15; float bv = c1b[j * H_ + col];
                    #pragma unroll
                    for (int r = 0; r < 4; ++r)
                        Cbuf[sidx(rbase + r, col)] = f2bf(siluf(c[r] + bv));
                }
                short8 a_t[4]; loadA(Cbuf, mrow, quad, a_t);
                #pragma unroll
                for (int s = 0; s < 8; ++s)
                    acc2[s] = gemm_s_acc(a_t, wl + IMG_C2 + j * 16384, s, l15, quad, acc2[s]);
            }
            // K: h_next = acc2 -> hreg + T3 image ; fold next-layer hmean partials
            #pragma unroll
            for (int s = 0; s < 8; ++s) {
                int col = s * 16 + l15;
                float p = 0.f;
                #pragma unroll
                for (int r = 0; r < 4; ++r) {
                    float v = acc2[s][r];
                    hreg[s][r] = v;
                    sm.T3[sidx(rbase + r, col)] = f2bf(v);
                    p += v;
                }
                p += __shfl_xor(p, 16);
                p += __shfl_xor(p, 32);
                if (quad == 0) part[wave * 128 + col] = f2bf(p);
            }
        }
        // no layer-end barrier: B1 at next layer top covers part/T3 visibility
    }

    // ---- head: FO -> T2 (own rows, no barrier) ; barrier ; gather -> out ----
    {
        short8 a_f[4]; loadA(sm.T3, mrow, quad, a_f);
        #pragma unroll 2
        for (int s = 0; s < 8; ++s) {
            f32x4 c = gemm_s(a_f, wimg + IMG_FO, s, l15, quad);
            int col = s * 16 + l15; float bv = fo_b1[col];
            #pragma unroll
            for (int r = 0; r < 4; ++r)
                sm.T2[sidx(rbase + r, col)] = f2bf(siluf(c[r] + bv));
        }
    }
    __syncthreads();
    if (tid < 192) {
        int n = tid / 3, j = tid - n * 3;
        float s = fo_b2[j];
        #pragma unroll 1
        for (int ch = 0; ch < 16; ++ch) {
            short8 v = *(const short8*)&sm.T2[fragoff(n, ch)];
            #pragma unroll
            for (int i = 0; i < 8; ++i)
                s = fmaf(bf2f((ushort_t)v[i]), fo_W2[(ch * 8 + i) * 3 + j], s);
        }
        out[b * 192 + tid] = s;
    }
}

extern "C" void kernel_launch(void* const* d_in, const int* in_sizes, int n_in,
                              void* d_out, int out_size, void* d_ws, size_t ws_size,
                              hipStream_t stream) {
    (void)in_sizes; (void)n_in; (void)out_size; (void)ws_size;
    convert_weights<<<248, 256, 0, stream>>>(
        (const float*)d_in[5], (const float*)d_in[7], (const float*)d_in[9],
        (const float*)d_in[12], (const float*)d_in[16], (const float*)d_in[18],
        (const float*)d_in[10], (const float*)d_in[20], (ushort_t*)d_ws);
    md17_fused_kernel<<<B_, NT, 0, stream>>>(
        (const float*)d_in[0], (const int*)d_in[1],
        (const float*)d_in[2], (const float*)d_in[3], (const float*)d_in[4],
        (const float*)d_in[6], (const float*)d_in[8],
        (const float*)d_in[11], (const float*)d_in[13],
        (const float*)d_in[14], (const float*)d_in[15],
        (const float*)d_in[17], (const float*)d_in[19],
        (const float*)d_in[21],
        (const float*)d_in[22], (const float*)d_in[23],
        (char*)d_ws, (float*)d_out);
}

// Round 10
// 1213.178 us; speedup vs baseline: 1.0475x; 1.0054x over previous
//
#include <hip/hip_runtime.h>

typedef unsigned short ushort_t;
typedef unsigned int uint_t;
typedef unsigned long long ull_t;
typedef __attribute__((ext_vector_type(8))) short short8;
typedef __attribute__((ext_vector_type(4))) float f32x4;

#define B_ 1024
#define N_ 64
#define H_ 128
#define NT 256

// bf16 weight-image element offsets
#define IMG_WI 0
#define IMG_WJ 16384
#define IMG_UW 32768
#define IMG_GS 49152
#define IMG_FT 65536
#define IMG_FB 81920
#define IMG_C1 98304
#define IMG_C2 163840
#define IMG_GMT 229376
#define IMG_RW 245760
#define IMG_L 249856
#define IMG_FO 999424

__device__ __forceinline__ ushort_t f2bf(float f) {
    // native RNE f32->bf16; bit-identical to the integer RNE sequence.
    return __builtin_bit_cast(ushort_t, (__bf16)f);
}
__device__ __forceinline__ float bf2f(ushort_t u) {
    union { uint_t i; float f; } v; v.i = ((uint_t)u) << 16; return v.f;
}
__device__ __forceinline__ float siluf(float x) { return x / (1.0f + __expf(-x)); }

// LDS swizzle: 16B-chunk c of row m stored at chunk c ^ (m&7)
__device__ __forceinline__ int sidx(int m, int k) {
    return m * H_ + (((k >> 3) ^ (m & 7)) << 3) + (k & 7);
}
__device__ __forceinline__ int fragoff(int m, int ch) {
    return m * H_ + ((ch ^ (m & 7)) << 3);
}

// ========== preamble: f32 weights -> transposed bf16 images ==============
// LDS 128x32 tile transpose. Reads coalesced (32x4B rows), writes
// vectorized 2x16B per thread.
extern "C" __global__ __launch_bounds__(256)
void convert_weights(const float* __restrict__ msg_W, const float* __restrict__ upd_W,
                     const float* __restrict__ gself_W, const float* __restrict__ fus_W,
                     const float* __restrict__ cb_W1, const float* __restrict__ cb_W2,
                     const float* __restrict__ gmean_W, const float* __restrict__ fo_W1,
                     ushort_t* __restrict__ wimg)
{
    __shared__ ushort_t tile[128][34];
    const int g = blockIdx.x;
    const int tid = threadIdx.x;
    const float* W; int ld = 128, k0 = 0, c0; ushort_t* dst;
    if (g >= 244) {
        int st = g - 244;
        W = fo_W1; c0 = st * 32; dst = wimg + IMG_FO + st * 4096;
    } else {
        const int l = g / 61, r = g - l * 61;
        ushort_t* base = wimg + l * IMG_L;
        if (r == 60) {                   // rW pad image: 4 sub-stages [32f][32k]
            const float* Wr = msg_W + l * 35328 + 256 * 128;
            ushort_t* drw = base + IMG_RW;
            for (int e = 0; e < 16; ++e) {
                int q = threadIdx.x * 16 + e;
                int sub = q >> 10, n = (q >> 5) & 31, k = q & 31;
                drw[q] = f2bf(k < 20 ? Wr[(size_t)k * 128 + sub * 32 + n] : 0.0f);
            }
            return;
        }
        int off, st;
        if      (r < 4)  { W = msg_W + l * 35328;            st = r;      off = IMG_WI;  c0 = st * 32; }
        else if (r < 8)  { W = msg_W + l * 35328;  k0 = 128; st = r - 4;  off = IMG_WJ;  c0 = st * 32; }
        else if (r < 12) { W = upd_W + l * 16384;            st = r - 8;  off = IMG_UW;  c0 = st * 32; }
        else if (r < 16) { W = gself_W + l * 16384;          st = r - 12; off = IMG_GS;  c0 = st * 32; }
        else if (r < 20) { W = fus_W + l * 32768;            st = r - 16; off = IMG_FT;  c0 = st * 32; }
        else if (r < 24) { W = fus_W + l * 32768;  k0 = 128; st = r - 20; off = IMG_FB;  c0 = st * 32; }
        else if (r < 40) { W = cb_W1 + l * 65536;  ld = 512; st = r - 24; off = IMG_C1;  c0 = st * 32; }
        else if (r < 56) { int j = (r - 40) >> 2; W = cb_W2 + l * 65536; k0 = j * 128;
                           st = r - 40; off = IMG_C2; c0 = ((r - 40) & 3) * 32; }
        else             { W = gmean_W + l * 16384;          st = r - 56; off = IMG_GMT; c0 = st * 32; }
        dst = base + off + st * 4096;
    }
    const int kr = tid >> 5, n = tid & 31;
    #pragma unroll
    for (int p = 0; p < 16; ++p) {
        int k = p * 8 + kr;
        tile[k][n] = f2bf(W[(size_t)(k0 + k) * ld + c0 + n]);
    }
    __syncthreads();
    {
        int n2 = tid >> 3, kk = (tid & 7) << 4;
        short8 v0, v1;
        #pragma unroll
        for (int e = 0; e < 8; ++e) v0[e] = (short)tile[kk + e][n2];
        #pragma unroll
        for (int e = 0; e < 8; ++e) v1[e] = (short)tile[kk + 8 + e][n2];
        *(short8*)(dst + n2 * 128 + kk) = v0;
        *(short8*)(dst + n2 * 128 + kk + 8) = v1;
    }
}

// ========== main fused kernel ==============================================
// EXACT R5 structure (best: 1197us fused / 1203 total) + ONE isolated diff:
// J-stage pipeline: (a) a_x hoisted out of the j-loop (T1/x-hat is invariant
// across chunks -- per-chunk reload was pure latency); (b) C1 scratch
// alternates T2 (j even) / T3 (j odd; T3's h image is dead in J: F consumed
// it, K rewrites it; T3 access is wave-private everywhere); (c) unroll 2 on
// the j-loop so chunk j+1's C1 MFMAs (independent buffer) fill chunk j's
// C2 LDS write->read turnaround.
// Ledger of refuted levers (do not retry): GMT-as-MFMA rewrite (R6 +80us),
// LDS diet for 3 blocks/CU (R7 +84us -- occupancy is register-pinned:
// gfx950 unified VGPR+AGPR demand > 256/wave; (NT,W) caps arch regs at
// 512/2W), rw-image LDS staging (R8 +50us, +8.6M bank conflicts; 8KB image
// is L1-resident), GEMV moved after B3 (R8/R9 -35..50us -- in R5 it already
// overlaps C's MFMAs).
struct __align__(16) Smem {
    ushort_t T1[N_ * H_];   // 16384B  scratch image (Gm/msum/glob/xhat)
    ushort_t T2[N_ * H_];   // 16384B  scratch image (hj/local/C1 even)
    ushort_t T3[N_ * H_];   // 16384B  layer-input h image (C1-odd scratch in J)
    float d[1024];          //  4096B
    float env[1024];        //  4096B
    ushort_t idx[1024];     //  2048B
    char u[2048];           // spos(768) | part bf16[512] | hmean@1024 | gvec@1536
};

// one output stage s (16 cols, col = s*16+l15), K=128: 4 B-frags from global
__device__ __forceinline__ f32x4 gemm_s(const short8 a[4], const ushort_t* __restrict__ img,
                                        int s, int l15, int quad)
{
    const ushort_t* base = img + ((s >> 1) << 12) + ((((s & 1) << 4) + l15) << 7) + quad * 8;
    short8 b0 = *(const short8*)(base);
    short8 b1 = *(const short8*)(base + 32);
    short8 b2 = *(const short8*)(base + 64);
    short8 b3 = *(const short8*)(base + 96);
    f32x4 c = {0.f, 0.f, 0.f, 0.f};
    c = __builtin_amdgcn_mfma_f32_16x16x32_bf16(a[0], b0, c, 0, 0, 0);
    c = __builtin_amdgcn_mfma_f32_16x16x32_bf16(a[1], b1, c, 0, 0, 0);
    c = __builtin_amdgcn_mfma_f32_16x16x32_bf16(a[2], b2, c, 0, 0, 0);
    c = __builtin_amdgcn_mfma_f32_16x16x32_bf16(a[3], b3, c, 0, 0, 0);
    return c;
}
__device__ __forceinline__ f32x4 gemm_s_acc(const short8 a[4], const ushort_t* __restrict__ img,
                                            int s, int l15, int quad, f32x4 c)
{
    const ushort_t* base = img + ((s >> 1) << 12) + ((((s & 1) << 4) + l15) << 7) + quad * 8;
    short8 b0 = *(const short8*)(base);
    short8 b1 = *(const short8*)(base + 32);
    short8 b2 = *(const short8*)(base + 64);
    short8 b3 = *(const short8*)(base + 96);
    c = __builtin_amdgcn_mfma_f32_16x16x32_bf16(a[0], b0, c, 0, 0, 0);
    c = __builtin_amdgcn_mfma_f32_16x16x32_bf16(a[1], b1, c, 0, 0, 0);
    c = __builtin_amdgcn_mfma_f32_16x16x32_bf16(a[2], b2, c, 0, 0, 0);
    c = __builtin_amdgcn_mfma_f32_16x16x32_bf16(a[3], b3, c, 0, 0, 0);
    return c;
}
__device__ __forceinline__ void loadA(const ushort_t* __restrict__ X, int mrow, int quad, short8 a[4]) {
    #pragma unroll
    for (int kc = 0; kc < 4; ++kc) a[kc] = *(const short8*)&X[fragoff(mrow, kc * 4 + quad)];
}

extern "C" __global__ __launch_bounds__(NT, 2)
void md17_fused_kernel(
    const float* __restrict__ positions, const int* __restrict__ atomic_numbers,
    const float* __restrict__ atom_embed, const float* __restrict__ pos_W,
    const float* __restrict__ pos_b,
    const float* __restrict__ msg_b, const float* __restrict__ upd_b,
    const float* __restrict__ g_b, const float* __restrict__ fus_b,
    const float* __restrict__ ln_g, const float* __restrict__ ln_b,
    const float* __restrict__ cb_b1, const float* __restrict__ cb_b2,
    const float* __restrict__ fo_b1,
    const float* __restrict__ fo_W2, const float* __restrict__ fo_b2,
    char* __restrict__ ws, float* __restrict__ out)
{
    __shared__ Smem sm;
    const int b = blockIdx.x;
    const int tid = threadIdx.x;
    const int wave = tid >> 6, lane = tid & 63;
    const int quad = lane >> 4, l15 = lane & 15;
    const int mrow = wave * 16 + l15;       // A-frag row (wave-owned)
    const int rbase = wave * 16 + quad * 4; // C-tile row base (wave-owned)

    const ushort_t* wimg = (const ushort_t*)ws;
    float* spos = (float*)sm.u;
    ushort_t* part = (ushort_t*)sm.u;       // [4][128] bf16 hmean partials
    float* hmean = (float*)(sm.u + 1024);
    float* gvec  = (float*)(sm.u + 1536);

    // residual stream, C-frag layout: hreg[s][r] = h[rbase+r][s*16+l15]
    float hreg[8][4];

    // ---- setup: positions -> LDS ----
    if (tid < 192) spos[tid] = positions[b * 192 + tid];
    __syncthreads();

    // ---- quad-parallel inline kNN: 16-lane group per atom ----
    {
        // candidates: lane owns atoms l15*4 .. l15*4+3 (lane order = index order)
        float cx[4], cy[4], cz[4];
        #pragma unroll
        for (int j = 0; j < 4; ++j) {
            cx[j] = spos[(l15 * 4 + j) * 3 + 0];
            cy[j] = spos[(l15 * 4 + j) * 3 + 1];
            cz[j] = spos[(l15 * 4 + j) * 3 + 2];
        }
        #pragma unroll 1
        for (int it = 0; it < 4; ++it) {
            const int n = wave * 16 + it * 4 + quad;   // this quad-group's atom
            float nx = spos[n * 3 + 0], ny = spos[n * 3 + 1], nz = spos[n * 3 + 2];
            float d2[4];
            #pragma unroll
            for (int j = 0; j < 4; ++j) {
                float dx = __fsub_rn(nx, cx[j]);
                float dy = __fsub_rn(ny, cy[j]);
                float dz = __fsub_rn(nz, cz[j]);
                d2[j] = __fadd_rn(__fadd_rn(__fmul_rn(dx, dx), __fmul_rn(dy, dy)),
                                  __fmul_rn(dz, dz));
                if (l15 * 4 + j == n) d2[j] = 1e30f;   // exclude self
            }
            #pragma unroll 1
            for (int k = 0; k < 16; ++k) {
                // strict < keeps lowest j on intra-lane ties
                float lm = d2[0];
                if (d2[1] < lm) lm = d2[1];
                if (d2[2] < lm) lm = d2[2];
                if (d2[3] < lm) lm = d2[3];
                float gm = lm;
                #pragma unroll
                for (int o = 1; o < 16; o <<= 1) gm = fminf(gm, __shfl_xor(gm, o));
                ull_t bal = __ballot(lm == gm);
                int wl = __ffsll((bal >> (quad * 16)) & 0xFFFFull) - 1;  // lowest lane
                if (l15 == wl) {
                    int jstar = 3;                      // lowest matching slot
                    if (d2[2] == gm) jstar = 2;
                    if (d2[1] == gm) jstar = 1;
                    if (d2[0] == gm) jstar = 0;
                    #pragma unroll
                    for (int j = 0; j < 4; ++j) if (j == jstar) d2[j] = 1e30f;
                    float dd = sqrtf(fmaxf(gm, 1e-12f));
                    sm.d[n * 16 + k] = dd;
                    sm.env[n * 16 + k] = (dd < 5.0f)
                        ? 0.5f * (__cosf(0.62831853071795864769f * dd) + 1.0f) : 0.0f;
                    sm.idx[n * 16 + k] = (ushort_t)(wl * 4 + jstar);
                }
            }
        }
    }

    // ---- embeddings, per-lane into hreg + T3 image ----
    {
        int an[4];
        #pragma unroll
        for (int r = 0; r < 4; ++r) an[r] = atomic_numbers[b * N_ + rbase + r];
        #pragma unroll
        for (int s = 0; s < 8; ++s) {
            int col = s * 16 + l15;
            #pragma unroll
            for (int r = 0; r < 4; ++r) {
                float v;
                if (s < 2) {                        // col < 32: atom-type embed
                    v = atom_embed[an[r] * 32 + col];
                } else {                            // col >= 32: position MLP
                    int j = col - 32;
                    v = pos_b[j];
                    #pragma unroll
                    for (int c = 0; c < 3; ++c)
                        v = fmaf(spos[(rbase + r) * 3 + c], pos_W[c * 96 + j], v);
                }
                hreg[s][r] = v;
                sm.T3[sidx(rbase + r, col)] = f2bf(v);
            }
        }
    }
    __syncthreads();
    // layer-0 hmean partials (stage A folded out of the loop)
    #pragma unroll
    for (int s = 0; s < 8; ++s) {
        int col = s * 16 + l15;
        float p = hreg[s][0] + hreg[s][1] + hreg[s][2] + hreg[s][3];
        p += __shfl_xor(p, 16);
        p += __shfl_xor(p, 32);
        if (quad == 0) part[wave * 128 + col] = f2bf(p);
    }

    #pragma unroll 1
    for (int l = 0; l < 4; ++l) {
        const ushort_t* wl = wimg + l * IMG_L;
        const float* mb  = msg_b + l * H_;
        const float* ub  = upd_b + l * H_;
        const float* gb  = g_b + l * H_;
        const float* fb  = fus_b + l * H_;
        const float* lg  = ln_g + l * H_;
        const float* lb  = ln_b + l * H_;
        const float* c1b = cb_b1 + l * 4 * H_;
        const float* c2b = cb_b2 + l * H_;

        __syncthreads();                                 // B1 (part visible)
        if (tid < H_)
            hmean[tid] = (bf2f(part[tid]) + bf2f(part[128 + tid])
                        + bf2f(part[256 + tid]) + bf2f(part[384 + tid])) * (1.0f / 64.0f);
        __syncthreads();                                 // B2

        // C: gvec GEMV (tid<128, overlaps C's MFMAs) ; a_h from T3 ;
        //    WI -> T1 (+mb) ; WJ -> T2
        if (tid < H_) {
            float s = gb[tid];
            const ushort_t* wrow = wl + IMG_GMT + tid * 128;
            for (int c = 0; c < 128; c += 8) {
                short8 w = *(const short8*)(wrow + c);
                #pragma unroll
                for (int i = 0; i < 8; ++i) s = fmaf(hmean[c + i], bf2f((ushort_t)w[i]), s);
            }
            gvec[tid] = s;
        }
        {
            short8 a_h[4]; loadA(sm.T3, mrow, quad, a_h);
            #pragma unroll 2
            for (int s = 0; s < 8; ++s) {
                f32x4 c = gemm_s(a_h, wl + IMG_WI, s, l15, quad);
                int col = s * 16 + l15; float bv = mb[col];
                #pragma unroll
                for (int r = 0; r < 4; ++r)
                    sm.T1[sidx(rbase + r, col)] = f2bf(c[r] + bv);
            }
            #pragma unroll 2
            for (int s = 0; s < 8; ++s) {
                f32x4 c = gemm_s(a_h, wl + IMG_WJ, s, l15, quad);
                int col = s * 16 + l15;
                #pragma unroll
                for (int r = 0; r < 4; ++r)
                    sm.T2[sidx(rbase + r, col)] = f2bf(c[r]);
            }
        }
        __syncthreads();                                 // B3 (Gm visible to all)

        // D: msum — whole wave per atom n = wave*16+g (own rows), in place in T1
        {
            float ccv[8];
            #pragma unroll
            for (int j = 0; j < 8; ++j)
                ccv[j] = (float)((double)(quad * 8 + j) * (5.0 / 19.0));
            #pragma unroll 1
            for (int g = 0; g < 16; ++g) {
                int n = wave * 16 + g;
                int jv[4]; float ev[4];
                #pragma unroll
                for (int r = 0; r < 4; ++r) {
                    int k = quad * 4 + r;
                    jv[r] = sm.idx[n * 16 + k];
                    ev[r] = sm.env[n * 16 + k];
                }
                float ddm = sm.d[n * 16 + l15];
                short8 arb;
                #pragma unroll
                for (int j = 0; j < 8; ++j) {
                    float t2 = ddm - ccv[j];
                    float rv = __expf(-10.0f * t2 * t2);
                    arb[j] = (short)((quad * 8 + j) < 20 ? f2bf(rv) : (ushort_t)0);
                }
                #pragma unroll
                for (int s = 0; s < 8; ++s) {
                    int col = s * 16 + l15;
                    const ushort_t* rbase_p = wl + IMG_RW + ((s >> 1) << 10)
                                            + ((((s & 1) << 4) + l15) << 5) + quad * 8;
                    short8 brw = *(const short8*)rbase_p;
                    f32x4 c = {0.f, 0.f, 0.f, 0.f};
                    c = __builtin_amdgcn_mfma_f32_16x16x32_bf16(arb, brw, c, 0, 0, 0);
                    float ai = bf2f(sm.T1[sidx(n, col)]);
                    float acc = 0.f;
                    #pragma unroll
                    for (int r = 0; r < 4; ++r) {
                        float gm = bf2f(sm.T2[sidx(jv[r], col)]);
                        acc = fmaf(siluf(ai + gm + c[r]), ev[r], acc);
                    }
                    acc += __shfl_xor(acc, 16);
                    acc += __shfl_xor(acc, 32);
                    if (quad == 0) sm.T1[sidx(n, col)] = f2bf(acc);
                }
            }
        }
        __syncthreads();                                 // B4 (Gm reads done; T2 free)

        // ---- free-run region: everything below touches only own rows ----

        // F: UW(a_m)+hreg -> T2 local ; GS(a_h reloaded from T3) + gvec -> T1 glob
        {
            short8 a_m[4]; loadA(sm.T1, mrow, quad, a_m);
            #pragma unroll
            for (int s = 0; s < 8; ++s) {
                f32x4 c = gemm_s(a_m, wl + IMG_UW, s, l15, quad);
                int col = s * 16 + l15; float bv = ub[col];
                #pragma unroll
                for (int r = 0; r < 4; ++r)
                    sm.T2[sidx(rbase + r, col)] = f2bf(hreg[s][r] + siluf(c[r] + bv));
            }
            short8 a_h[4]; loadA(sm.T3, mrow, quad, a_h);
            #pragma unroll 2
            for (int s = 0; s < 8; ++s) {
                f32x4 c = gemm_s(a_h, wl + IMG_GS, s, l15, quad);
                int col = s * 16 + l15; float gv = gvec[col];
                #pragma unroll
                for (int r = 0; r < 4; ++r)
                    sm.T1[sidx(rbase + r, col)] = f2bf(siluf(c[r] + gv));
            }
        }

        // G: fused = silu([local|glob]@[FT;FB]+fb) -> hreg ; LN sums in regs
        float sr[4] = {0.f, 0.f, 0.f, 0.f}, qr[4] = {0.f, 0.f, 0.f, 0.f};
        {
            short8 a_t[4];
            loadA(sm.T2, mrow, quad, a_t);               // local
            #pragma unroll
            for (int s = 0; s < 8; ++s) {
                f32x4 c = gemm_s(a_t, wl + IMG_FT, s, l15, quad);
                #pragma unroll
                for (int r = 0; r < 4; ++r) hreg[s][r] = c[r];  // residual h is dead here
            }
            loadA(sm.T1, mrow, quad, a_t);               // glob
            #pragma unroll
            for (int s = 0; s < 8; ++s) {
                f32x4 c = gemm_s(a_t, wl + IMG_FB, s, l15, quad);
                int col = s * 16 + l15; float bv = fb[col];
                #pragma unroll
                for (int r = 0; r < 4; ++r) {
                    float v = siluf(hreg[s][r] + c[r] + bv);
                    hreg[s][r] = v;
                    sr[r] += v; qr[r] += v * v;
                }
            }
            #pragma unroll
            for (int o = 1; o < 16; o <<= 1) {
                #pragma unroll
                for (int r = 0; r < 4; ++r) {
                    sr[r] += __shfl_xor(sr[r], o);
                    qr[r] += __shfl_xor(qr[r], o);
                }
            }
        }

        // H: LN normalize (wave-local) -> T1 (x-hat)
        #pragma unroll
        for (int r = 0; r < 4; ++r) {
            float mu = sr[r] * (1.0f / 128.0f);
            float var = qr[r] * (1.0f / 128.0f) - mu * mu;
            float rs = rsqrtf(var + 1e-5f);
            int row = rbase + r;
            #pragma unroll
            for (int s = 0; s < 8; ++s) {
                int col = s * 16 + l15;
                sm.T1[sidx(row, col)] = f2bf((hreg[s][r] - mu) * rs * lg[col] + lb[col]);
            }
        }

        // J: Clifford MLP, 4 K-chunks. a_x (x-hat) loaded ONCE (T1 invariant
        // across chunks); C1 scratch alternates T2 / T3 (T3 dead here, wave-
        // private); unroll 2 overlaps chunk j+1's C1 with chunk j's C2
        // turnaround. acc2 SEEDED with residual + c2b (hreg dead across loop).
        {
            short8 a_x[4]; loadA(sm.T1, mrow, quad, a_x);
            f32x4 acc2[8];
            #pragma unroll
            for (int s = 0; s < 8; ++s) {
                int col = s * 16 + l15; float bv = c2b[col];
                #pragma unroll
                for (int r = 0; r < 4; ++r) acc2[s][r] = hreg[s][r] + bv;
            }
            #pragma unroll 2
            for (int j = 0; j < 4; ++j) {
                ushort_t* Cbuf = (j & 1) ? sm.T3 : sm.T2;
                #pragma unroll 2
                for (int s = 0; s < 8; ++s) {
                    f32x4 c = gemm_s(a_x, wl + IMG_C1 + j * 16384, s, l15, quad);
                    int col = s * 16 + l15; float bv = c1b[j * H_ + col];
                    #pragma unroll
                    for (int r = 0; r < 4; ++r)
                        Cbuf[sidx(rbase + r, col)] = f2bf(siluf(c[r] + bv));
                }
                short8 a_t[4]; loadA(Cbuf, mrow, quad, a_t);
                #pragma unroll
                for (int s = 0; s < 8; ++s)
                    acc2[s] = gemm_s_acc(a_t, wl + IMG_C2 + j * 16384, s, l15, quad, acc2[s]);
            }
            // K: h_next = acc2 -> hreg + T3 image ; fold next-layer hmean partials
            #pragma unroll
            for (int s = 0; s < 8; ++s) {
                int col = s * 16 + l15;
                float p = 0.f;
                #pragma unroll
                for (int r = 0; r < 4; ++r) {
                    float v = acc2[s][r];
                    hreg[s][r] = v;
                    sm.T3[sidx(rbase + r, col)] = f2bf(v);
                    p += v;
                }
                p += __shfl_xor(p, 16);
                p += __shfl_xor(p, 32);
                if (quad == 0) part[wave * 128 + col] = f2bf(p);
            }
        }
        // no layer-end barrier: B1 at next layer top covers part/T3 visibility
    }

    // ---- head: FO -> T2 (own rows, no barrier) ; barrier ; gather -> out ----
    {
        short8 a_f[4]; loadA(sm.T3, mrow, quad, a_f);
        #pragma unroll 2
        for (int s = 0; s < 8; ++s) {
            f32x4 c = gemm_s(a_f, wimg + IMG_FO, s, l15, quad);
            int col = s * 16 + l15; float bv = fo_b1[col];
            #pragma unroll
            for (int r = 0; r < 4; ++r)
                sm.T2[sidx(rbase + r, col)] = f2bf(siluf(c[r] + bv));
        }
    }
    __syncthreads();
    if (tid < 192) {
        int n = tid / 3, j = tid - n * 3;
        float s = fo_b2[j];
        #pragma unroll 1
        for (int ch = 0; ch < 16; ++ch) {
            short8 v = *(const short8*)&sm.T2[fragoff(n, ch)];
            #pragma unroll
            for (int i = 0; i < 8; ++i)
                s = fmaf(bf2f((ushort_t)v[i]), fo_W2[(ch * 8 + i) * 3 + j], s);
        }
        out[b * 192 + tid] = s;
    }
}

extern "C" void kernel_launch(void* const* d_in, const int* in_sizes, int n_in,
                              void* d_out, int out_size, void* d_ws, size_t ws_size,
                              hipStream_t stream) {
    (void)in_sizes; (void)n_in; (void)out_size; (void)ws_size;
    convert_weights<<<248, 256, 0, stream>>>(
        (const float*)d_in[5], (const float*)d_in[7], (const float*)d_in[9],
        (const float*)d_in[12], (const float*)d_in[16], (const float*)d_in[18],
        (const float*)d_in[10], (const float*)d_in[20], (ushort_t*)d_ws);
    md17_fused_kernel<<<B_, NT, 0, stream>>>(
        (const float*)d_in[0], (const int*)d_in[1],
        (const float*)d_in[2], (const float*)d_in[3], (const float*)d_in[4],
        (const float*)d_in[6], (const float*)d_in[8],
        (const float*)d_in[11], (const float*)d_in[13],
        (const float*)d_in[14], (const float*)d_in[15],
        (const float*)d_in[17], (const float*)d_in[19],
        (const float*)d_in[21],
        (const float*)d_in[22], (const float*)d_in[23],
        (char*)d_ws, (float*)d_out);
}

// Round 11
// 1204.347 us; speedup vs baseline: 1.0552x; 1.0073x over previous
//
#include <hip/hip_runtime.h>

typedef unsigned short ushort_t;
typedef unsigned int uint_t;
typedef unsigned long long ull_t;
typedef __attribute__((ext_vector_type(8))) short short8;
typedef __attribute__((ext_vector_type(4))) float f32x4;

#define B_ 1024
#define N_ 64
#define H_ 128
#define NT 256

// bf16 weight-image element offsets
#define IMG_WI 0
#define IMG_WJ 16384
#define IMG_UW 32768
#define IMG_GS 49152
#define IMG_FT 65536
#define IMG_FB 81920
#define IMG_C1 98304
#define IMG_C2 163840
#define IMG_GMT 229376
#define IMG_RW 245760
#define IMG_L 249856
#define IMG_FO 999424

__device__ __forceinline__ ushort_t f2bf(float f) {
    // native RNE f32->bf16; bit-identical to the integer RNE sequence.
    return __builtin_bit_cast(ushort_t, (__bf16)f);
}
__device__ __forceinline__ float bf2f(ushort_t u) {
    union { uint_t i; float f; } v; v.i = ((uint_t)u) << 16; return v.f;
}
__device__ __forceinline__ float siluf(float x) { return x / (1.0f + __expf(-x)); }

// LDS swizzle: 16B-chunk c of row m stored at chunk c ^ (m&7)
__device__ __forceinline__ int sidx(int m, int k) {
    return m * H_ + (((k >> 3) ^ (m & 7)) << 3) + (k & 7);
}
__device__ __forceinline__ int fragoff(int m, int ch) {
    return m * H_ + ((ch ^ (m & 7)) << 3);
}

// ========== preamble: f32 weights -> transposed bf16 images ==============
// LDS 128x32 tile transpose. Reads coalesced (32x4B rows), writes
// vectorized 2x16B per thread.
extern "C" __global__ __launch_bounds__(256)
void convert_weights(const float* __restrict__ msg_W, const float* __restrict__ upd_W,
                     const float* __restrict__ gself_W, const float* __restrict__ fus_W,
                     const float* __restrict__ cb_W1, const float* __restrict__ cb_W2,
                     const float* __restrict__ gmean_W, const float* __restrict__ fo_W1,
                     ushort_t* __restrict__ wimg)
{
    __shared__ ushort_t tile[128][34];
    const int g = blockIdx.x;
    const int tid = threadIdx.x;
    const float* W; int ld = 128, k0 = 0, c0; ushort_t* dst;
    if (g >= 244) {
        int st = g - 244;
        W = fo_W1; c0 = st * 32; dst = wimg + IMG_FO + st * 4096;
    } else {
        const int l = g / 61, r = g - l * 61;
        ushort_t* base = wimg + l * IMG_L;
        if (r == 60) {                   // rW pad image: 4 sub-stages [32f][32k]
            const float* Wr = msg_W + l * 35328 + 256 * 128;
            ushort_t* drw = base + IMG_RW;
            for (int e = 0; e < 16; ++e) {
                int q = threadIdx.x * 16 + e;
                int sub = q >> 10, n = (q >> 5) & 31, k = q & 31;
                drw[q] = f2bf(k < 20 ? Wr[(size_t)k * 128 + sub * 32 + n] : 0.0f);
            }
            return;
        }
        int off, st;
        if      (r < 4)  { W = msg_W + l * 35328;            st = r;      off = IMG_WI;  c0 = st * 32; }
        else if (r < 8)  { W = msg_W + l * 35328;  k0 = 128; st = r - 4;  off = IMG_WJ;  c0 = st * 32; }
        else if (r < 12) { W = upd_W + l * 16384;            st = r - 8;  off = IMG_UW;  c0 = st * 32; }
        else if (r < 16) { W = gself_W + l * 16384;          st = r - 12; off = IMG_GS;  c0 = st * 32; }
        else if (r < 20) { W = fus_W + l * 32768;            st = r - 16; off = IMG_FT;  c0 = st * 32; }
        else if (r < 24) { W = fus_W + l * 32768;  k0 = 128; st = r - 20; off = IMG_FB;  c0 = st * 32; }
        else if (r < 40) { W = cb_W1 + l * 65536;  ld = 512; st = r - 24; off = IMG_C1;  c0 = st * 32; }
        else if (r < 56) { int j = (r - 40) >> 2; W = cb_W2 + l * 65536; k0 = j * 128;
                           st = r - 40; off = IMG_C2; c0 = ((r - 40) & 3) * 32; }
        else             { W = gmean_W + l * 16384;          st = r - 56; off = IMG_GMT; c0 = st * 32; }
        dst = base + off + st * 4096;
    }
    const int kr = tid >> 5, n = tid & 31;
    #pragma unroll
    for (int p = 0; p < 16; ++p) {
        int k = p * 8 + kr;
        tile[k][n] = f2bf(W[(size_t)(k0 + k) * ld + c0 + n]);
    }
    __syncthreads();
    {
        int n2 = tid >> 3, kk = (tid & 7) << 4;
        short8 v0, v1;
        #pragma unroll
        for (int e = 0; e < 8; ++e) v0[e] = (short)tile[kk + e][n2];
        #pragma unroll
        for (int e = 0; e < 8; ++e) v1[e] = (short)tile[kk + 8 + e][n2];
        *(short8*)(dst + n2 * 128 + kk) = v0;
        *(short8*)(dst + n2 * 128 + kk + 8) = v1;
    }
}

// ========== main fused kernel ==============================================
// SESSION-FINAL = R5 (best measured: 1197us fused / 1203us total; baseline
// was 1484us). 256 threads = 4 waves; wave w owns rows w*16..+15, all cols.
// Residual stream in REGISTERS (hreg[8][4], C-frag layout). kNN inlined,
// QUAD-PARALLEL (16-lane group per atom; xor1/2/4/8 DPP butterflies).
// __launch_bounds__(NT,2): occupancy register-pinned at 2 waves/SIMD
// (gfx950 unified VGPR+AGPR; uncapped demand >256 total/wave; (NT,3) caps
// arch regs at 84 -> catastrophic spill). ~20 dword/thread residual spill
// accepted.
// Refuted-lever ledger (do not retry): GMT-as-MFMA rewrite (+80us);
// LDS diet for 3 blk/CU (+84us, occupancy is reg-pinned not LDS-pinned);
// rw-image LDS staging (+50us, L1-resident + 8.6M bank conflicts);
// GEMV after B3 (+35-50us, already overlaps C); J a_x-hoist/dbuf/unroll2
// (+15us, turnaround already hidden by co-resident block). This is the
// structural latency floor of the 4-barrier row-split stage graph at
// 2 waves/SIMD (NOT a HW roofline: MfmaUtil 5.5%, HBM 0.3%).
struct __align__(16) Smem {
    ushort_t T1[N_ * H_];   // 16384B  scratch image (Gm/msum/glob/xhat)
    ushort_t T2[N_ * H_];   // 16384B  scratch image (hj/local/C1)
    ushort_t T3[N_ * H_];   // 16384B  layer-input h image
    float d[1024];          //  4096B
    float env[1024];        //  4096B
    ushort_t idx[1024];     //  2048B
    char u[2048];           // spos(768) | part bf16[512] | hmean@1024 | gvec@1536
};

// one output stage s (16 cols, col = s*16+l15), K=128: 4 B-frags from global
__device__ __forceinline__ f32x4 gemm_s(const short8 a[4], const ushort_t* __restrict__ img,
                                        int s, int l15, int quad)
{
    const ushort_t* base = img + ((s >> 1) << 12) + ((((s & 1) << 4) + l15) << 7) + quad * 8;
    short8 b0 = *(const short8*)(base);
    short8 b1 = *(const short8*)(base + 32);
    short8 b2 = *(const short8*)(base + 64);
    short8 b3 = *(const short8*)(base + 96);
    f32x4 c = {0.f, 0.f, 0.f, 0.f};
    c = __builtin_amdgcn_mfma_f32_16x16x32_bf16(a[0], b0, c, 0, 0, 0);
    c = __builtin_amdgcn_mfma_f32_16x16x32_bf16(a[1], b1, c, 0, 0, 0);
    c = __builtin_amdgcn_mfma_f32_16x16x32_bf16(a[2], b2, c, 0, 0, 0);
    c = __builtin_amdgcn_mfma_f32_16x16x32_bf16(a[3], b3, c, 0, 0, 0);
    return c;
}
__device__ __forceinline__ f32x4 gemm_s_acc(const short8 a[4], const ushort_t* __restrict__ img,
                                            int s, int l15, int quad, f32x4 c)
{
    const ushort_t* base = img + ((s >> 1) << 12) + ((((s & 1) << 4) + l15) << 7) + quad * 8;
    short8 b0 = *(const short8*)(base);
    short8 b1 = *(const short8*)(base + 32);
    short8 b2 = *(const short8*)(base + 64);
    short8 b3 = *(const short8*)(base + 96);
    c = __builtin_amdgcn_mfma_f32_16x16x32_bf16(a[0], b0, c, 0, 0, 0);
    c = __builtin_amdgcn_mfma_f32_16x16x32_bf16(a[1], b1, c, 0, 0, 0);
    c = __builtin_amdgcn_mfma_f32_16x16x32_bf16(a[2], b2, c, 0, 0, 0);
    c = __builtin_amdgcn_mfma_f32_16x16x32_bf16(a[3], b3, c, 0, 0, 0);
    return c;
}
__device__ __forceinline__ void loadA(const ushort_t* __restrict__ X, int mrow, int quad, short8 a[4]) {
    #pragma unroll
    for (int kc = 0; kc < 4; ++kc) a[kc] = *(const short8*)&X[fragoff(mrow, kc * 4 + quad)];
}

extern "C" __global__ __launch_bounds__(NT, 2)
void md17_fused_kernel(
    const float* __restrict__ positions, const int* __restrict__ atomic_numbers,
    const float* __restrict__ atom_embed, const float* __restrict__ pos_W,
    const float* __restrict__ pos_b,
    const float* __restrict__ msg_b, const float* __restrict__ upd_b,
    const float* __restrict__ g_b, const float* __restrict__ fus_b,
    const float* __restrict__ ln_g, const float* __restrict__ ln_b,
    const float* __restrict__ cb_b1, const float* __restrict__ cb_b2,
    const float* __restrict__ fo_b1,
    const float* __restrict__ fo_W2, const float* __restrict__ fo_b2,
    char* __restrict__ ws, float* __restrict__ out)
{
    __shared__ Smem sm;
    const int b = blockIdx.x;
    const int tid = threadIdx.x;
    const int wave = tid >> 6, lane = tid & 63;
    const int quad = lane >> 4, l15 = lane & 15;
    const int mrow = wave * 16 + l15;       // A-frag row (wave-owned)
    const int rbase = wave * 16 + quad * 4; // C-tile row base (wave-owned)

    const ushort_t* wimg = (const ushort_t*)ws;
    float* spos = (float*)sm.u;
    ushort_t* part = (ushort_t*)sm.u;       // [4][128] bf16 hmean partials
    float* hmean = (float*)(sm.u + 1024);
    float* gvec  = (float*)(sm.u + 1536);

    // residual stream, C-frag layout: hreg[s][r] = h[rbase+r][s*16+l15]
    float hreg[8][4];

    // ---- setup: positions -> LDS ----
    if (tid < 192) spos[tid] = positions[b * 192 + tid];
    __syncthreads();

    // ---- quad-parallel inline kNN: 16-lane group per atom ----
    {
        // candidates: lane owns atoms l15*4 .. l15*4+3 (lane order = index order)
        float cx[4], cy[4], cz[4];
        #pragma unroll
        for (int j = 0; j < 4; ++j) {
            cx[j] = spos[(l15 * 4 + j) * 3 + 0];
            cy[j] = spos[(l15 * 4 + j) * 3 + 1];
            cz[j] = spos[(l15 * 4 + j) * 3 + 2];
        }
        #pragma unroll 1
        for (int it = 0; it < 4; ++it) {
            const int n = wave * 16 + it * 4 + quad;   // this quad-group's atom
            float nx = spos[n * 3 + 0], ny = spos[n * 3 + 1], nz = spos[n * 3 + 2];
            float d2[4];
            #pragma unroll
            for (int j = 0; j < 4; ++j) {
                float dx = __fsub_rn(nx, cx[j]);
                float dy = __fsub_rn(ny, cy[j]);
                float dz = __fsub_rn(nz, cz[j]);
                d2[j] = __fadd_rn(__fadd_rn(__fmul_rn(dx, dx), __fmul_rn(dy, dy)),
                                  __fmul_rn(dz, dz));
                if (l15 * 4 + j == n) d2[j] = 1e30f;   // exclude self
            }
            #pragma unroll 1
            for (int k = 0; k < 16; ++k) {
                // strict < keeps lowest j on intra-lane ties
                float lm = d2[0];
                if (d2[1] < lm) lm = d2[1];
                if (d2[2] < lm) lm = d2[2];
                if (d2[3] < lm) lm = d2[3];
                float gm = lm;
                #pragma unroll
                for (int o = 1; o < 16; o <<= 1) gm = fminf(gm, __shfl_xor(gm, o));
                ull_t bal = __ballot(lm == gm);
                int wl = __ffsll((bal >> (quad * 16)) & 0xFFFFull) - 1;  // lowest lane
                if (l15 == wl) {
                    int jstar = 3;                      // lowest matching slot
                    if (d2[2] == gm) jstar = 2;
                    if (d2[1] == gm) jstar = 1;
                    if (d2[0] == gm) jstar = 0;
                    #pragma unroll
                    for (int j = 0; j < 4; ++j) if (j == jstar) d2[j] = 1e30f;
                    float dd = sqrtf(fmaxf(gm, 1e-12f));
                    sm.d[n * 16 + k] = dd;
                    sm.env[n * 16 + k] = (dd < 5.0f)
                        ? 0.5f * (__cosf(0.62831853071795864769f * dd) + 1.0f) : 0.0f;
                    sm.idx[n * 16 + k] = (ushort_t)(wl * 4 + jstar);
                }
            }
        }
    }

    // ---- embeddings, per-lane into hreg + T3 image ----
    {
        int an[4];
        #pragma unroll
        for (int r = 0; r < 4; ++r) an[r] = atomic_numbers[b * N_ + rbase + r];
        #pragma unroll
        for (int s = 0; s < 8; ++s) {
            int col = s * 16 + l15;
            #pragma unroll
            for (int r = 0; r < 4; ++r) {
                float v;
                if (s < 2) {                        // col < 32: atom-type embed
                    v = atom_embed[an[r] * 32 + col];
                } else {                            // col >= 32: position MLP
                    int j = col - 32;
                    v = pos_b[j];
                    #pragma unroll
                    for (int c = 0; c < 3; ++c)
                        v = fmaf(spos[(rbase + r) * 3 + c], pos_W[c * 96 + j], v);
                }
                hreg[s][r] = v;
                sm.T3[sidx(rbase + r, col)] = f2bf(v);
            }
        }
    }
    __syncthreads();
    // layer-0 hmean partials (stage A folded out of the loop)
    #pragma unroll
    for (int s = 0; s < 8; ++s) {
        int col = s * 16 + l15;
        float p = hreg[s][0] + hreg[s][1] + hreg[s][2] + hreg[s][3];
        p += __shfl_xor(p, 16);
        p += __shfl_xor(p, 32);
        if (quad == 0) part[wave * 128 + col] = f2bf(p);
    }

    #pragma unroll 1
    for (int l = 0; l < 4; ++l) {
        const ushort_t* wl = wimg + l * IMG_L;
        const float* mb  = msg_b + l * H_;
        const float* ub  = upd_b + l * H_;
        const float* gb  = g_b + l * H_;
        const float* fb  = fus_b + l * H_;
        const float* lg  = ln_g + l * H_;
        const float* lb  = ln_b + l * H_;
        const float* c1b = cb_b1 + l * 4 * H_;
        const float* c2b = cb_b2 + l * H_;

        __syncthreads();                                 // B1 (part visible)
        if (tid < H_)
            hmean[tid] = (bf2f(part[tid]) + bf2f(part[128 + tid])
                        + bf2f(part[256 + tid]) + bf2f(part[384 + tid])) * (1.0f / 64.0f);
        __syncthreads();                                 // B2

        // C: gvec GEMV (tid<128, overlaps C's MFMAs) ; a_h from T3 ;
        //    WI -> T1 (+mb) ; WJ -> T2
        if (tid < H_) {
            float s = gb[tid];
            const ushort_t* wrow = wl + IMG_GMT + tid * 128;
            for (int c = 0; c < 128; c += 8) {
                short8 w = *(const short8*)(wrow + c);
                #pragma unroll
                for (int i = 0; i < 8; ++i) s = fmaf(hmean[c + i], bf2f((ushort_t)w[i]), s);
            }
            gvec[tid] = s;
        }
        {
            short8 a_h[4]; loadA(sm.T3, mrow, quad, a_h);
            #pragma unroll 2
            for (int s = 0; s < 8; ++s) {
                f32x4 c = gemm_s(a_h, wl + IMG_WI, s, l15, quad);
                int col = s * 16 + l15; float bv = mb[col];
                #pragma unroll
                for (int r = 0; r < 4; ++r)
                    sm.T1[sidx(rbase + r, col)] = f2bf(c[r] + bv);
            }
            #pragma unroll 2
            for (int s = 0; s < 8; ++s) {
                f32x4 c = gemm_s(a_h, wl + IMG_WJ, s, l15, quad);
                int col = s * 16 + l15;
                #pragma unroll
                for (int r = 0; r < 4; ++r)
                    sm.T2[sidx(rbase + r, col)] = f2bf(c[r]);
            }
        }
        __syncthreads();                                 // B3 (Gm visible to all)

        // D: msum — whole wave per atom n = wave*16+g (own rows), in place in T1
        {
            float ccv[8];
            #pragma unroll
            for (int j = 0; j < 8; ++j)
                ccv[j] = (float)((double)(quad * 8 + j) * (5.0 / 19.0));
            #pragma unroll 1
            for (int g = 0; g < 16; ++g) {
                int n = wave * 16 + g;
                int jv[4]; float ev[4];
                #pragma unroll
                for (int r = 0; r < 4; ++r) {
                    int k = quad * 4 + r;
                    jv[r] = sm.idx[n * 16 + k];
                    ev[r] = sm.env[n * 16 + k];
                }
                float ddm = sm.d[n * 16 + l15];
                short8 arb;
                #pragma unroll
                for (int j = 0; j < 8; ++j) {
                    float t2 = ddm - ccv[j];
                    float rv = __expf(-10.0f * t2 * t2);
                    arb[j] = (short)((quad * 8 + j) < 20 ? f2bf(rv) : (ushort_t)0);
                }
                #pragma unroll
                for (int s = 0; s < 8; ++s) {
                    int col = s * 16 + l15;
                    const ushort_t* rbase_p = wl + IMG_RW + ((s >> 1) << 10)
                                            + ((((s & 1) << 4) + l15) << 5) + quad * 8;
                    short8 brw = *(const short8*)rbase_p;
                    f32x4 c = {0.f, 0.f, 0.f, 0.f};
                    c = __builtin_amdgcn_mfma_f32_16x16x32_bf16(arb, brw, c, 0, 0, 0);
                    float ai = bf2f(sm.T1[sidx(n, col)]);
                    float acc = 0.f;
                    #pragma unroll
                    for (int r = 0; r < 4; ++r) {
                        float gm = bf2f(sm.T2[sidx(jv[r], col)]);
                        acc = fmaf(siluf(ai + gm + c[r]), ev[r], acc);
                    }
                    acc += __shfl_xor(acc, 16);
                    acc += __shfl_xor(acc, 32);
                    if (quad == 0) sm.T1[sidx(n, col)] = f2bf(acc);
                }
            }
        }
        __syncthreads();                                 // B4 (Gm reads done; T2 free)

        // ---- free-run region: everything below touches only own rows ----

        // F: UW(a_m)+hreg -> T2 local ; GS(a_h reloaded from T3) + gvec -> T1 glob
        {
            short8 a_m[4]; loadA(sm.T1, mrow, quad, a_m);
            #pragma unroll
            for (int s = 0; s < 8; ++s) {
                f32x4 c = gemm_s(a_m, wl + IMG_UW, s, l15, quad);
                int col = s * 16 + l15; float bv = ub[col];
                #pragma unroll
                for (int r = 0; r < 4; ++r)
                    sm.T2[sidx(rbase + r, col)] = f2bf(hreg[s][r] + siluf(c[r] + bv));
            }
            short8 a_h[4]; loadA(sm.T3, mrow, quad, a_h);
            #pragma unroll 2
            for (int s = 0; s < 8; ++s) {
                f32x4 c = gemm_s(a_h, wl + IMG_GS, s, l15, quad);
                int col = s * 16 + l15; float gv = gvec[col];
                #pragma unroll
                for (int r = 0; r < 4; ++r)
                    sm.T1[sidx(rbase + r, col)] = f2bf(siluf(c[r] + gv));
            }
        }

        // G: fused = silu([local|glob]@[FT;FB]+fb) -> hreg ; LN sums in regs
        float sr[4] = {0.f, 0.f, 0.f, 0.f}, qr[4] = {0.f, 0.f, 0.f, 0.f};
        {
            short8 a_t[4];
            loadA(sm.T2, mrow, quad, a_t);               // local
            #pragma unroll
            for (int s = 0; s < 8; ++s) {
                f32x4 c = gemm_s(a_t, wl + IMG_FT, s, l15, quad);
                #pragma unroll
                for (int r = 0; r < 4; ++r) hreg[s][r] = c[r];  // residual h is dead here
            }
            loadA(sm.T1, mrow, quad, a_t);               // glob
            #pragma unroll
            for (int s = 0; s < 8; ++s) {
                f32x4 c = gemm_s(a_t, wl + IMG_FB, s, l15, quad);
                int col = s * 16 + l15; float bv = fb[col];
                #pragma unroll
                for (int r = 0; r < 4; ++r) {
                    float v = siluf(hreg[s][r] + c[r] + bv);
                    hreg[s][r] = v;
                    sr[r] += v; qr[r] += v * v;
                }
            }
            #pragma unroll
            for (int o = 1; o < 16; o <<= 1) {
                #pragma unroll
                for (int r = 0; r < 4; ++r) {
                    sr[r] += __shfl_xor(sr[r], o);
                    qr[r] += __shfl_xor(qr[r], o);
                }
            }
        }

        // H: LN normalize (wave-local) -> T1 (x-hat)
        #pragma unroll
        for (int r = 0; r < 4; ++r) {
            float mu = sr[r] * (1.0f / 128.0f);
            float var = qr[r] * (1.0f / 128.0f) - mu * mu;
            float rs = rsqrtf(var + 1e-5f);
            int row = rbase + r;
            #pragma unroll
            for (int s = 0; s < 8; ++s) {
                int col = s * 16 + l15;
                sm.T1[sidx(row, col)] = f2bf((hreg[s][r] - mu) * rs * lg[col] + lb[col]);
            }
        }

        // J: Clifford MLP, 4 K-chunks; C1 -> T2; C2 accumulates into acc2.
        // acc2 SEEDED with residual + c2b (hreg dead across j-loop); a_x
        // reloaded from T1 each chunk.
        {
            f32x4 acc2[8];
            #pragma unroll
            for (int s = 0; s < 8; ++s) {
                int col = s * 16 + l15; float bv = c2b[col];
                #pragma unroll
                for (int r = 0; r < 4; ++r) acc2[s][r] = hreg[s][r] + bv;
            }
            #pragma unroll 1
            for (int j = 0; j < 4; ++j) {
                short8 a_x[4]; loadA(sm.T1, mrow, quad, a_x);
                #pragma unroll 2
                for (int s = 0; s < 8; ++s) {
                    f32x4 c = gemm_s(a_x, wl + IMG_C1 + j * 16384, s, l15, quad);
                    int col = s * 16 + l15; float bv = c1b[j * H_ + col];
                    #pragma unroll
                    for (int r = 0; r < 4; ++r)
                        sm.T2[sidx(rbase + r, col)] = f2bf(siluf(c[r] + bv));
                }
                short8 a_t[4]; loadA(sm.T2, mrow, quad, a_t);
                #pragma unroll
                for (int s = 0; s < 8; ++s)
                    acc2[s] = gemm_s_acc(a_t, wl + IMG_C2 + j * 16384, s, l15, quad, acc2[s]);
            }
            // K: h_next = acc2 -> hreg + T3 image ; fold next-layer hmean partials
            #pragma unroll
            for (int s = 0; s < 8; ++s) {
                int col = s * 16 + l15;
                float p = 0.f;
                #pragma unroll
                for (int r = 0; r < 4; ++r) {
                    float v = acc2[s][r];
                    hreg[s][r] = v;
                    sm.T3[sidx(rbase + r, col)] = f2bf(v);
                    p += v;
                }
                p += __shfl_xor(p, 16);
                p += __shfl_xor(p, 32);
                if (quad == 0) part[wave * 128 + col] = f2bf(p);
            }
        }
        // no layer-end barrier: B1 at next layer top covers part/T3 visibility
    }

    // ---- head: FO -> T2 (own rows, no barrier) ; barrier ; gather -> out ----
    {
        short8 a_f[4]; loadA(sm.T3, mrow, quad, a_f);
        #pragma unroll 2
        for (int s = 0; s < 8; ++s) {
            f32x4 c = gemm_s(a_f, wimg + IMG_FO, s, l15, quad);
            int col = s * 16 + l15; float bv = fo_b1[col];
            #pragma unroll
            for (int r = 0; r < 4; ++r)
                sm.T2[sidx(rbase + r, col)] = f2bf(siluf(c[r] + bv));
        }
    }
    __syncthreads();
    if (tid < 192) {
        int n = tid / 3, j = tid - n * 3;
        float s = fo_b2[j];
        #pragma unroll 1
        for (int ch = 0; ch < 16; ++ch) {
            short8 v = *(const short8*)&sm.T2[fragoff(n, ch)];
            #pragma unroll
            for (int i = 0; i < 8; ++i)
                s = fmaf(bf2f((ushort_t)v[i]), fo_W2[(ch * 8 + i) * 3 + j], s);
        }
        out[b * 192 + tid] = s;
    }
}

extern "C" void kernel_launch(void* const* d_in, const int* in_sizes, int n_in,
                              void* d_out, int out_size, void* d_ws, size_t ws_size,
                              hipStream_t stream) {
    (void)in_sizes; (void)n_in; (void)out_size; (void)ws_size;
    convert_weights<<<248, 256, 0, stream>>>(
        (const float*)d_in[5], (const float*)d_in[7], (const float*)d_in[9],
        (const float*)d_in[12], (const float*)d_in[16], (const float*)d_in[18],
        (const float*)d_in[10], (const float*)d_in[20], (ushort_t*)d_ws);
    md17_fused_kernel<<<B_, NT, 0, stream>>>(
        (const float*)d_in[0], (const int*)d_in[1],
        (const float*)d_in[2], (const float*)d_in[3], (const float*)d_in[4],
        (const float*)d_in[6], (const float*)d_in[8],
        (const float*)d_in[11], (const float*)d_in[13],
        (const float*)d_in[14], (const float*)d_in[15],
        (const float*)d_in[17], (const float*)d_in[19],
        (const float*)d_in[21],
        (const float*)d_in[22], (const float*)d_in[23],
        (char*)d_ws, (float*)d_out);
}